// Round 3
// baseline (25413.148 us; speedup 1.0000x reference)
//
#include <hip/hip_runtime.h>

#define TT 512
#define BB 1024
#define FF 32
#define HH 64
#define GG 256   // 4*H gates per direction

// Static device scratch (ws_size-independent). Fully overwritten every call.
__device__ float g_h1[(size_t)TT * BB * 2 * HH];   // [T][B][128], 256 MB
__device__ float g_hf[(size_t)BB * HH];            // [B][64] final fwd h of layer1

__device__ __forceinline__ float fsigm(float x) {
    float e = __builtin_amdgcn_exp2f(x * -1.44269504088896f);
    return __builtin_amdgcn_rcpf(1.0f + e);
}
__device__ __forceinline__ float ftanh(float x) {
    float e = __builtin_amdgcn_exp2f(x * -2.88539008177793f);
    return 2.0f * __builtin_amdgcn_rcpf(1.0f + e) - 1.0f;
}

// 4-batch MAC on one float4 weight chunk. All operands are named scalars /
// wave-uniform LDS broadcasts — no per-thread arrays anywhere (anti-scratch).
#define MAC4(W, P0, P1, P2, P3, K) do{                                   \
    float4 v_;                                                           \
    v_ = (P0)[K]; acc0 += W.x*v_.x; acc0 += W.y*v_.y; acc0 += W.z*v_.z; acc0 += W.w*v_.w; \
    v_ = (P1)[K]; acc1 += W.x*v_.x; acc1 += W.y*v_.y; acc1 += W.z*v_.z; acc1 += W.w*v_.w; \
    v_ = (P2)[K]; acc2 += W.x*v_.x; acc2 += W.y*v_.y; acc2 += W.z*v_.z; acc2 += W.w*v_.w; \
    v_ = (P3)[K]; acc3 += W.x*v_.x; acc3 += W.y*v_.y; acc3 += W.z*v_.z; acc3 += W.w*v_.w; \
}while(0)

// ---------------------------------------------------------------------------
// Layer 0 (both directions): fused input GEMM + recurrent scan.
// 512 blocks (dir = bid&1, batch tile of 4), 256 threads = one gate row each.
// Weights live in 24 named float4 registers per thread.
// ---------------------------------------------------------------------------
__global__ __launch_bounds__(256, 2) void lstm_layer0(
    const float* __restrict__ x,      // [B][T][F]
    const float* __restrict__ w_ih,   // [2][G][F]
    const float* __restrict__ w_hh,   // [2][G][H]
    const float* __restrict__ b_ih,   // [2][G]
    const float* __restrict__ b_hh)   // [2][G]
{
    const int tid  = threadIdx.x;
    const int dir  = blockIdx.x & 1;
    const int b0   = (blockIdx.x >> 1) * 4;

    __shared__ __align__(16) float x_lds[2][4][FF];   // double-buffered
    __shared__ __align__(16) float h_lds[4][HH];
    __shared__ __align__(16) float gact[4][GG];

    // Named weight registers (time-invariant).
    const float4* pwi = (const float4*)(w_ih + ((size_t)dir * GG + tid) * FF);
    float4 wi0 = pwi[0], wi1 = pwi[1], wi2 = pwi[2], wi3 = pwi[3],
           wi4 = pwi[4], wi5 = pwi[5], wi6 = pwi[6], wi7 = pwi[7];
    const float4* pwh = (const float4*)(w_hh + ((size_t)dir * GG + tid) * HH);
    float4 wh0 = pwh[0],  wh1 = pwh[1],  wh2 = pwh[2],  wh3 = pwh[3],
           wh4 = pwh[4],  wh5 = pwh[5],  wh6 = pwh[6],  wh7 = pwh[7],
           wh8 = pwh[8],  wh9 = pwh[9],  wh10 = pwh[10], wh11 = pwh[11],
           wh12 = pwh[12], wh13 = pwh[13], wh14 = pwh[14], wh15 = pwh[15];
    const float bias = b_ih[dir * GG + tid] + b_hh[dir * GG + tid];

    h_lds[tid >> 6][tid & 63] = 0.0f;
    float c_reg = 0.0f;
    const int cb = tid >> 6, cj = tid & 63;
    const bool is_g = ((tid >> 6) == 2);   // gates 128..191 -> tanh (wave-uniform)

    // stage x(step 0) into buffer 0
    const int lb = tid >> 5, lf = tid & 31;        // staging role (tid < 128)
    if (tid < 128) {
        int t0 = (dir == 0) ? 0 : (TT - 1);
        x_lds[0][lb][lf] = x[((size_t)(b0 + lb) * TT + t0) * FF + lf];
    }

    for (int s = 0; s < TT; ++s) {
        const int t = (dir == 0) ? s : (TT - 1 - s);
        __syncthreads();   // [A] x_lds[s&1] + h_lds(prev step) ready

        // prefetch next step's x into a register (hidden behind the MAC loop)
        float xpre = 0.0f;
        if (tid < 128 && s + 1 < TT) {
            int tn = (dir == 0) ? (s + 1) : (TT - 2 - s);
            xpre = x[((size_t)(b0 + lb) * TT + tn) * FF + lf];
        }

        const float4* xb0 = (const float4*)x_lds[s & 1][0];
        const float4* xb1 = (const float4*)x_lds[s & 1][1];
        const float4* xb2 = (const float4*)x_lds[s & 1][2];
        const float4* xb3 = (const float4*)x_lds[s & 1][3];
        const float4* hb0 = (const float4*)h_lds[0];
        const float4* hb1 = (const float4*)h_lds[1];
        const float4* hb2 = (const float4*)h_lds[2];
        const float4* hb3 = (const float4*)h_lds[3];

        float acc0 = bias, acc1 = bias, acc2 = bias, acc3 = bias;
        MAC4(wi0, xb0, xb1, xb2, xb3, 0);  MAC4(wi1, xb0, xb1, xb2, xb3, 1);
        MAC4(wi2, xb0, xb1, xb2, xb3, 2);  MAC4(wi3, xb0, xb1, xb2, xb3, 3);
        MAC4(wi4, xb0, xb1, xb2, xb3, 4);  MAC4(wi5, xb0, xb1, xb2, xb3, 5);
        MAC4(wi6, xb0, xb1, xb2, xb3, 6);  MAC4(wi7, xb0, xb1, xb2, xb3, 7);
        MAC4(wh0, hb0, hb1, hb2, hb3, 0);  MAC4(wh1, hb0, hb1, hb2, hb3, 1);
        MAC4(wh2, hb0, hb1, hb2, hb3, 2);  MAC4(wh3, hb0, hb1, hb2, hb3, 3);
        MAC4(wh4, hb0, hb1, hb2, hb3, 4);  MAC4(wh5, hb0, hb1, hb2, hb3, 5);
        MAC4(wh6, hb0, hb1, hb2, hb3, 6);  MAC4(wh7, hb0, hb1, hb2, hb3, 7);
        MAC4(wh8, hb0, hb1, hb2, hb3, 8);  MAC4(wh9, hb0, hb1, hb2, hb3, 9);
        MAC4(wh10, hb0, hb1, hb2, hb3, 10); MAC4(wh11, hb0, hb1, hb2, hb3, 11);
        MAC4(wh12, hb0, hb1, hb2, hb3, 12); MAC4(wh13, hb0, hb1, hb2, hb3, 13);
        MAC4(wh14, hb0, hb1, hb2, hb3, 14); MAC4(wh15, hb0, hb1, hb2, hb3, 15);

        gact[0][tid] = is_g ? ftanh(acc0) : fsigm(acc0);
        gact[1][tid] = is_g ? ftanh(acc1) : fsigm(acc1);
        gact[2][tid] = is_g ? ftanh(acc2) : fsigm(acc2);
        gact[3][tid] = is_g ? ftanh(acc3) : fsigm(acc3);
        __syncthreads();   // [B] gates ready; all x_lds/h_lds reads done

        if (tid < 128 && s + 1 < TT) x_lds[(s + 1) & 1][lb][lf] = xpre;

        {
            float ig = gact[cb][cj];
            float fg = gact[cb][HH + cj];
            float gg = gact[cb][2 * HH + cj];
            float og = gact[cb][3 * HH + cj];
            c_reg = fg * c_reg + ig * gg;
            float h = og * ftanh(c_reg);
            h_lds[cb][cj] = h;
            g_h1[((size_t)t * BB + (b0 + cb)) * (2 * HH) + dir * HH + cj] = h;
        }
        // next [A] orders h_lds/x_lds writes vs next step's reads
    }
}

// ---------------------------------------------------------------------------
// Layer 1 forward scan. K = 192 split across 2 thread groups of 256
// (24 named float4 regs each), LDS reduction. 256 blocks x 512 threads.
// ---------------------------------------------------------------------------
__global__ __launch_bounds__(512, 2) void lstm_layer1_fwd(
    const float* __restrict__ w_ih,   // [2][G][128]  (dir 0)
    const float* __restrict__ w_hh,   // [2][G][64]
    const float* __restrict__ b_ih,
    const float* __restrict__ b_hh)
{
    const int tid  = threadIdx.x;
    const int grp  = tid >> 8;        // 0: k=0..95, 1: k=96..191 (wave-uniform)
    const int gate = tid & 255;
    const int b0   = blockIdx.x * 4;

    __shared__ __align__(16) float x_lds[2][4][128];  // double-buffered
    __shared__ __align__(16) float h_lds[4][HH];
    __shared__ __align__(16) float part[2][4][GG];
    __shared__ __align__(16) float gact[4][GG];

    float4 w0, w1, w2, w3, w4, w5, w6, w7, w8, w9, w10, w11,
           w12, w13, w14, w15, w16, w17, w18, w19, w20, w21, w22, w23;
    if (grp == 0) {
        const float4* p = (const float4*)(w_ih + (size_t)gate * 128);
        w0 = p[0];  w1 = p[1];  w2 = p[2];  w3 = p[3];  w4 = p[4];  w5 = p[5];
        w6 = p[6];  w7 = p[7];  w8 = p[8];  w9 = p[9];  w10 = p[10]; w11 = p[11];
        w12 = p[12]; w13 = p[13]; w14 = p[14]; w15 = p[15]; w16 = p[16]; w17 = p[17];
        w18 = p[18]; w19 = p[19]; w20 = p[20]; w21 = p[21]; w22 = p[22]; w23 = p[23];
    } else {
        const float4* p = (const float4*)(w_ih + (size_t)gate * 128 + 96);
        w0 = p[0]; w1 = p[1]; w2 = p[2]; w3 = p[3];
        w4 = p[4]; w5 = p[5]; w6 = p[6]; w7 = p[7];
        const float4* q = (const float4*)(w_hh + (size_t)gate * HH);
        w8 = q[0];  w9 = q[1];  w10 = q[2]; w11 = q[3]; w12 = q[4]; w13 = q[5];
        w14 = q[6]; w15 = q[7]; w16 = q[8]; w17 = q[9]; w18 = q[10]; w19 = q[11];
        w20 = q[12]; w21 = q[13]; w22 = q[14]; w23 = q[15];
    }
    const float bias = (grp == 0) ? (b_ih[gate] + b_hh[gate]) : 0.0f;

    if (tid < 256) h_lds[tid >> 6][tid & 63] = 0.0f;
    float c_reg = 0.0f;
    const int cb = tid >> 6, cj = tid & 63;     // valid when tid < 256
    const int sb = tid >> 7, sc = tid & 127;    // staging role (all 512)

    // stage h1 row t=0 into buffer 0
    x_lds[0][sb][sc] = g_h1[((size_t)0 * BB + (b0 + sb)) * 128 + sc];

    for (int t = 0; t < TT; ++t) {
        __syncthreads();   // [A] x_lds[t&1] + h_lds ready

        float xpre = 0.0f;
        if (t + 1 < TT)
            xpre = g_h1[((size_t)(t + 1) * BB + (b0 + sb)) * 128 + sc];

        const float4* xb0 = (const float4*)x_lds[t & 1][0];
        const float4* xb1 = (const float4*)x_lds[t & 1][1];
        const float4* xb2 = (const float4*)x_lds[t & 1][2];
        const float4* xb3 = (const float4*)x_lds[t & 1][3];
        const float4* hb0 = (const float4*)h_lds[0];
        const float4* hb1 = (const float4*)h_lds[1];
        const float4* hb2 = (const float4*)h_lds[2];
        const float4* hb3 = (const float4*)h_lds[3];

        float acc0 = bias, acc1 = bias, acc2 = bias, acc3 = bias;
        if (grp == 0) {
            MAC4(w0, xb0, xb1, xb2, xb3, 0);   MAC4(w1, xb0, xb1, xb2, xb3, 1);
            MAC4(w2, xb0, xb1, xb2, xb3, 2);   MAC4(w3, xb0, xb1, xb2, xb3, 3);
            MAC4(w4, xb0, xb1, xb2, xb3, 4);   MAC4(w5, xb0, xb1, xb2, xb3, 5);
            MAC4(w6, xb0, xb1, xb2, xb3, 6);   MAC4(w7, xb0, xb1, xb2, xb3, 7);
            MAC4(w8, xb0, xb1, xb2, xb3, 8);   MAC4(w9, xb0, xb1, xb2, xb3, 9);
            MAC4(w10, xb0, xb1, xb2, xb3, 10); MAC4(w11, xb0, xb1, xb2, xb3, 11);
            MAC4(w12, xb0, xb1, xb2, xb3, 12); MAC4(w13, xb0, xb1, xb2, xb3, 13);
            MAC4(w14, xb0, xb1, xb2, xb3, 14); MAC4(w15, xb0, xb1, xb2, xb3, 15);
            MAC4(w16, xb0, xb1, xb2, xb3, 16); MAC4(w17, xb0, xb1, xb2, xb3, 17);
            MAC4(w18, xb0, xb1, xb2, xb3, 18); MAC4(w19, xb0, xb1, xb2, xb3, 19);
            MAC4(w20, xb0, xb1, xb2, xb3, 20); MAC4(w21, xb0, xb1, xb2, xb3, 21);
            MAC4(w22, xb0, xb1, xb2, xb3, 22); MAC4(w23, xb0, xb1, xb2, xb3, 23);
        } else {
            MAC4(w0, xb0, xb1, xb2, xb3, 24);  MAC4(w1, xb0, xb1, xb2, xb3, 25);
            MAC4(w2, xb0, xb1, xb2, xb3, 26);  MAC4(w3, xb0, xb1, xb2, xb3, 27);
            MAC4(w4, xb0, xb1, xb2, xb3, 28);  MAC4(w5, xb0, xb1, xb2, xb3, 29);
            MAC4(w6, xb0, xb1, xb2, xb3, 30);  MAC4(w7, xb0, xb1, xb2, xb3, 31);
            MAC4(w8, hb0, hb1, hb2, hb3, 0);   MAC4(w9, hb0, hb1, hb2, hb3, 1);
            MAC4(w10, hb0, hb1, hb2, hb3, 2);  MAC4(w11, hb0, hb1, hb2, hb3, 3);
            MAC4(w12, hb0, hb1, hb2, hb3, 4);  MAC4(w13, hb0, hb1, hb2, hb3, 5);
            MAC4(w14, hb0, hb1, hb2, hb3, 6);  MAC4(w15, hb0, hb1, hb2, hb3, 7);
            MAC4(w16, hb0, hb1, hb2, hb3, 8);  MAC4(w17, hb0, hb1, hb2, hb3, 9);
            MAC4(w18, hb0, hb1, hb2, hb3, 10); MAC4(w19, hb0, hb1, hb2, hb3, 11);
            MAC4(w20, hb0, hb1, hb2, hb3, 12); MAC4(w21, hb0, hb1, hb2, hb3, 13);
            MAC4(w22, hb0, hb1, hb2, hb3, 14); MAC4(w23, hb0, hb1, hb2, hb3, 15);
        }
        part[grp][0][gate] = acc0;
        part[grp][1][gate] = acc1;
        part[grp][2][gate] = acc2;
        part[grp][3][gate] = acc3;
        __syncthreads();   // [B] partials ready; x_lds/h_lds reads done

        {
            const bool is_g = (gate >= 128) && (gate < 192);
#pragma unroll
            for (int bb = 0; bb < 2; ++bb) {
                int b = grp * 2 + bb;
                float sgt = part[0][b][gate] + part[1][b][gate];
                gact[b][gate] = is_g ? ftanh(sgt) : fsigm(sgt);
            }
        }
        __syncthreads();   // [C] gact ready

        if (t + 1 < TT) x_lds[(t + 1) & 1][sb][sc] = xpre;

        if (tid < 256) {
            float ig = gact[cb][cj];
            float fg = gact[cb][HH + cj];
            float gg = gact[cb][2 * HH + cj];
            float og = gact[cb][3 * HH + cj];
            c_reg = fg * c_reg + ig * gg;
            float h = og * ftanh(c_reg);
            h_lds[cb][cj] = h;
            if (t == TT - 1) g_hf[(size_t)(b0 + cb) * HH + cj] = h;
        }
    }
}

// ---------------------------------------------------------------------------
// Layer 1 backward single step (zero state on h1[T-1]) + FC head.
// ---------------------------------------------------------------------------
__global__ __launch_bounds__(256, 2) void lstm_final(
    const float* __restrict__ w_ih,   // [2][G][128] (dir 1)
    const float* __restrict__ b_ih,
    const float* __restrict__ b_hh,
    const float* __restrict__ fc_w,   // [2][128]
    const float* __restrict__ fc_b,   // [2]
    float* __restrict__ out)          // [B][2]
{
    const int tid = threadIdx.x;
    const int b0  = blockIdx.x * 4;

    __shared__ __align__(16) float x_lds[4][128];
    __shared__ __align__(16) float gact[4][GG];
    __shared__ __align__(16) float last[4][128];

#pragma unroll
    for (int r = 0; r < 2; ++r) {
        int idx = tid + r * 256;
        int b = idx >> 7, col = idx & 127;
        x_lds[b][col] = g_h1[((size_t)(TT - 1) * BB + (b0 + b)) * 128 + col];
    }

    const float4* p = (const float4*)(w_ih + ((size_t)GG + tid) * 128);
    float4 w0 = p[0],  w1 = p[1],  w2 = p[2],  w3 = p[3],  w4 = p[4],  w5 = p[5],
           w6 = p[6],  w7 = p[7],  w8 = p[8],  w9 = p[9],  w10 = p[10], w11 = p[11],
           w12 = p[12], w13 = p[13], w14 = p[14], w15 = p[15], w16 = p[16], w17 = p[17],
           w18 = p[18], w19 = p[19], w20 = p[20], w21 = p[21], w22 = p[22], w23 = p[23],
           w24 = p[24], w25 = p[25], w26 = p[26], w27 = p[27], w28 = p[28], w29 = p[29],
           w30 = p[30], w31 = p[31];
    const float bias = b_ih[GG + tid] + b_hh[GG + tid];
    __syncthreads();

    const float4* xb0 = (const float4*)x_lds[0];
    const float4* xb1 = (const float4*)x_lds[1];
    const float4* xb2 = (const float4*)x_lds[2];
    const float4* xb3 = (const float4*)x_lds[3];

    float acc0 = bias, acc1 = bias, acc2 = bias, acc3 = bias;
    MAC4(w0, xb0, xb1, xb2, xb3, 0);   MAC4(w1, xb0, xb1, xb2, xb3, 1);
    MAC4(w2, xb0, xb1, xb2, xb3, 2);   MAC4(w3, xb0, xb1, xb2, xb3, 3);
    MAC4(w4, xb0, xb1, xb2, xb3, 4);   MAC4(w5, xb0, xb1, xb2, xb3, 5);
    MAC4(w6, xb0, xb1, xb2, xb3, 6);   MAC4(w7, xb0, xb1, xb2, xb3, 7);
    MAC4(w8, xb0, xb1, xb2, xb3, 8);   MAC4(w9, xb0, xb1, xb2, xb3, 9);
    MAC4(w10, xb0, xb1, xb2, xb3, 10); MAC4(w11, xb0, xb1, xb2, xb3, 11);
    MAC4(w12, xb0, xb1, xb2, xb3, 12); MAC4(w13, xb0, xb1, xb2, xb3, 13);
    MAC4(w14, xb0, xb1, xb2, xb3, 14); MAC4(w15, xb0, xb1, xb2, xb3, 15);
    MAC4(w16, xb0, xb1, xb2, xb3, 16); MAC4(w17, xb0, xb1, xb2, xb3, 17);
    MAC4(w18, xb0, xb1, xb2, xb3, 18); MAC4(w19, xb0, xb1, xb2, xb3, 19);
    MAC4(w20, xb0, xb1, xb2, xb3, 20); MAC4(w21, xb0, xb1, xb2, xb3, 21);
    MAC4(w22, xb0, xb1, xb2, xb3, 22); MAC4(w23, xb0, xb1, xb2, xb3, 23);
    MAC4(w24, xb0, xb1, xb2, xb3, 24); MAC4(w25, xb0, xb1, xb2, xb3, 25);
    MAC4(w26, xb0, xb1, xb2, xb3, 26); MAC4(w27, xb0, xb1, xb2, xb3, 27);
    MAC4(w28, xb0, xb1, xb2, xb3, 28); MAC4(w29, xb0, xb1, xb2, xb3, 29);
    MAC4(w30, xb0, xb1, xb2, xb3, 30); MAC4(w31, xb0, xb1, xb2, xb3, 31);

    const bool is_g = ((tid >> 6) == 2);
    gact[0][tid] = is_g ? ftanh(acc0) : fsigm(acc0);
    gact[1][tid] = is_g ? ftanh(acc1) : fsigm(acc1);
    gact[2][tid] = is_g ? ftanh(acc2) : fsigm(acc2);
    gact[3][tid] = is_g ? ftanh(acc3) : fsigm(acc3);
    __syncthreads();

    {
        const int cb = tid >> 6, cj = tid & 63;
        float ig = gact[cb][cj];
        float gg = gact[cb][2 * HH + cj];
        float og = gact[cb][3 * HH + cj];
        float c = ig * gg;
        float h = og * ftanh(c);
        last[cb][HH + cj] = h;
        last[cb][cj] = g_hf[(size_t)(b0 + cb) * HH + cj];
    }
    __syncthreads();

    if (tid < 8) {
        int b = tid >> 1, o = tid & 1;
        float a = fc_b[o];
#pragma unroll
        for (int j = 0; j < 128; ++j) a += fc_w[o * 128 + j] * last[b][j];
        out[(size_t)(b0 + b) * 2 + o] = a;
    }
}

extern "C" void kernel_launch(void* const* d_in, const int* in_sizes, int n_in,
                              void* d_out, int out_size, void* d_ws, size_t ws_size,
                              hipStream_t stream) {
    const float* x     = (const float*)d_in[0];
    const float* w_ih0 = (const float*)d_in[1];
    const float* w_hh0 = (const float*)d_in[2];
    const float* b_ih0 = (const float*)d_in[3];
    const float* b_hh0 = (const float*)d_in[4];
    const float* w_ih1 = (const float*)d_in[5];
    const float* w_hh1 = (const float*)d_in[6];
    const float* b_ih1 = (const float*)d_in[7];
    const float* b_hh1 = (const float*)d_in[8];
    const float* fc_w  = (const float*)d_in[9];
    const float* fc_b  = (const float*)d_in[10];
    float* out = (float*)d_out;

    lstm_layer0<<<512, 256, 0, stream>>>(x, w_ih0, w_hh0, b_ih0, b_hh0);
    lstm_layer1_fwd<<<256, 512, 0, stream>>>(w_ih1, w_hh1, b_ih1, b_hh1);
    lstm_final<<<256, 256, 0, stream>>>(w_ih1, b_ih1, b_hh1, fc_w, fc_b, out);
}

// Round 6
// 22030.283 us; speedup vs baseline: 1.1536x; 1.1536x over previous
//
#include <hip/hip_runtime.h>

#define TT 512
#define BB 1024
#define FF 32
#define HH 64
#define GG 256   // 4*H gates per direction

// Static device scratch (ws_size-independent). Fully overwritten every call.
__device__ float g_h1[(size_t)TT * BB * 2 * HH];   // [T][B][128], 256 MB
__device__ float g_hf[(size_t)BB * HH];            // [B][64] final fwd h of layer1

__device__ __forceinline__ float fsigm(float x) {
    float e = __builtin_amdgcn_exp2f(x * -1.44269504088896f);
    return __builtin_amdgcn_rcpf(1.0f + e);
}
__device__ __forceinline__ float ftanh(float x) {
    float e = __builtin_amdgcn_exp2f(x * -2.88539008177793f);
    return 2.0f * __builtin_amdgcn_rcpf(1.0f + e) - 1.0f;
}

// Pin a float4 into VGPRs, component-wise (scalar "+v" is supported; the
// 128-bit tuple form is not — r5 compile error). Executed每 iteration, this
// makes the weights loop-carried register state: the compiler can neither
// sink the global loads into the loop (r3: 23GB/dispatch re-fetch) nor
// spill-and-forget (r2: 36GB scratch writes).
#define PIN(v) asm volatile("" : "+v"(v.x), "+v"(v.y), "+v"(v.z), "+v"(v.w))

// 4-batch MAC on one float4 weight chunk. All operands are named scalars /
// wave-uniform LDS broadcasts.
#define MAC4(W, P0, P1, P2, P3, K) do{                                   \
    float4 v_;                                                           \
    v_ = (P0)[K]; acc0 += W.x*v_.x; acc0 += W.y*v_.y; acc0 += W.z*v_.z; acc0 += W.w*v_.w; \
    v_ = (P1)[K]; acc1 += W.x*v_.x; acc1 += W.y*v_.y; acc1 += W.z*v_.z; acc1 += W.w*v_.w; \
    v_ = (P2)[K]; acc2 += W.x*v_.x; acc2 += W.y*v_.y; acc2 += W.z*v_.z; acc2 += W.w*v_.w; \
    v_ = (P3)[K]; acc3 += W.x*v_.x; acc3 += W.y*v_.y; acc3 += W.z*v_.z; acc3 += W.w*v_.w; \
}while(0)

// ---------------------------------------------------------------------------
// Layer 0 (both directions): fused input GEMM + recurrent scan.
// 512 blocks (dir = bid&1, batch tile of 4) x 256 threads = one gate row each.
// 24 pinned float4 weight registers per thread.
// ---------------------------------------------------------------------------
__global__ __launch_bounds__(256, 2) void lstm_layer0(
    const float* __restrict__ x,      // [B][T][F]
    const float* __restrict__ w_ih,   // [2][G][F]
    const float* __restrict__ w_hh,   // [2][G][H]
    const float* __restrict__ b_ih,   // [2][G]
    const float* __restrict__ b_hh)   // [2][G]
{
    const int tid  = threadIdx.x;
    const int dir  = blockIdx.x & 1;
    const int b0   = (blockIdx.x >> 1) * 4;

    __shared__ __align__(16) float x_lds[2][4][FF];   // double-buffered
    __shared__ __align__(16) float h_lds[4][HH];
    __shared__ __align__(16) float gact[4][GG];

    const float4* pwi = (const float4*)(w_ih + ((size_t)dir * GG + tid) * FF);
    float4 wi0 = pwi[0], wi1 = pwi[1], wi2 = pwi[2], wi3 = pwi[3],
           wi4 = pwi[4], wi5 = pwi[5], wi6 = pwi[6], wi7 = pwi[7];
    const float4* pwh = (const float4*)(w_hh + ((size_t)dir * GG + tid) * HH);
    float4 wh0 = pwh[0],  wh1 = pwh[1],  wh2 = pwh[2],  wh3 = pwh[3],
           wh4 = pwh[4],  wh5 = pwh[5],  wh6 = pwh[6],  wh7 = pwh[7],
           wh8 = pwh[8],  wh9 = pwh[9],  wh10 = pwh[10], wh11 = pwh[11],
           wh12 = pwh[12], wh13 = pwh[13], wh14 = pwh[14], wh15 = pwh[15];
    const float bias = b_ih[dir * GG + tid] + b_hh[dir * GG + tid];

    h_lds[tid >> 6][tid & 63] = 0.0f;
    float c_reg = 0.0f;
    const int cb = tid >> 6, cj = tid & 63;
    const bool is_g = ((tid >> 6) == 2);   // gates 128..191 -> tanh (wave-uniform)

    const int lb = tid >> 5, lf = tid & 31;        // staging role (tid < 128)
    if (tid < 128) {
        int t0 = (dir == 0) ? 0 : (TT - 1);
        x_lds[0][lb][lf] = x[((size_t)(b0 + lb) * TT + t0) * FF + lf];
    }

    for (int s = 0; s < TT; ++s) {
        const int t = (dir == 0) ? s : (TT - 1 - s);
        __syncthreads();   // [A] x_lds[s&1] + h_lds(prev step) ready

        PIN(wi0); PIN(wi1); PIN(wi2); PIN(wi3);
        PIN(wi4); PIN(wi5); PIN(wi6); PIN(wi7);
        PIN(wh0); PIN(wh1); PIN(wh2); PIN(wh3);
        PIN(wh4); PIN(wh5); PIN(wh6); PIN(wh7);
        PIN(wh8); PIN(wh9); PIN(wh10); PIN(wh11);
        PIN(wh12); PIN(wh13); PIN(wh14); PIN(wh15);

        // prefetch next step's x into a register (hidden behind the MAC loop)
        float xpre = 0.0f;
        if (tid < 128 && s + 1 < TT) {
            int tn = (dir == 0) ? (s + 1) : (TT - 2 - s);
            xpre = x[((size_t)(b0 + lb) * TT + tn) * FF + lf];
        }

        const float4* xb0 = (const float4*)x_lds[s & 1][0];
        const float4* xb1 = (const float4*)x_lds[s & 1][1];
        const float4* xb2 = (const float4*)x_lds[s & 1][2];
        const float4* xb3 = (const float4*)x_lds[s & 1][3];
        const float4* hb0 = (const float4*)h_lds[0];
        const float4* hb1 = (const float4*)h_lds[1];
        const float4* hb2 = (const float4*)h_lds[2];
        const float4* hb3 = (const float4*)h_lds[3];

        float acc0 = bias, acc1 = bias, acc2 = bias, acc3 = bias;
        MAC4(wi0, xb0, xb1, xb2, xb3, 0);  MAC4(wi1, xb0, xb1, xb2, xb3, 1);
        MAC4(wi2, xb0, xb1, xb2, xb3, 2);  MAC4(wi3, xb0, xb1, xb2, xb3, 3);
        MAC4(wi4, xb0, xb1, xb2, xb3, 4);  MAC4(wi5, xb0, xb1, xb2, xb3, 5);
        MAC4(wi6, xb0, xb1, xb2, xb3, 6);  MAC4(wi7, xb0, xb1, xb2, xb3, 7);
        MAC4(wh0, hb0, hb1, hb2, hb3, 0);  MAC4(wh1, hb0, hb1, hb2, hb3, 1);
        MAC4(wh2, hb0, hb1, hb2, hb3, 2);  MAC4(wh3, hb0, hb1, hb2, hb3, 3);
        MAC4(wh4, hb0, hb1, hb2, hb3, 4);  MAC4(wh5, hb0, hb1, hb2, hb3, 5);
        MAC4(wh6, hb0, hb1, hb2, hb3, 6);  MAC4(wh7, hb0, hb1, hb2, hb3, 7);
        MAC4(wh8, hb0, hb1, hb2, hb3, 8);  MAC4(wh9, hb0, hb1, hb2, hb3, 9);
        MAC4(wh10, hb0, hb1, hb2, hb3, 10); MAC4(wh11, hb0, hb1, hb2, hb3, 11);
        MAC4(wh12, hb0, hb1, hb2, hb3, 12); MAC4(wh13, hb0, hb1, hb2, hb3, 13);
        MAC4(wh14, hb0, hb1, hb2, hb3, 14); MAC4(wh15, hb0, hb1, hb2, hb3, 15);

        gact[0][tid] = is_g ? ftanh(acc0) : fsigm(acc0);
        gact[1][tid] = is_g ? ftanh(acc1) : fsigm(acc1);
        gact[2][tid] = is_g ? ftanh(acc2) : fsigm(acc2);
        gact[3][tid] = is_g ? ftanh(acc3) : fsigm(acc3);
        __syncthreads();   // [B] gates ready; all x_lds/h_lds reads done

        if (tid < 128 && s + 1 < TT) x_lds[(s + 1) & 1][lb][lf] = xpre;

        {
            float ig = gact[cb][cj];
            float fg = gact[cb][HH + cj];
            float gg = gact[cb][2 * HH + cj];
            float og = gact[cb][3 * HH + cj];
            c_reg = fg * c_reg + ig * gg;
            float h = og * ftanh(c_reg);
            h_lds[cb][cj] = h;
            g_h1[((size_t)t * BB + (b0 + cb)) * (2 * HH) + dir * HH + cj] = h;
        }
        // next [A] orders h_lds/x_lds writes vs next step's reads
    }
}

// ---------------------------------------------------------------------------
// Layer 1 forward scan. K = 192 split across 2 thread groups of 256
// (24 pinned float4 regs each), LDS reduction. 256 blocks x 512 threads.
// ---------------------------------------------------------------------------
__global__ __launch_bounds__(512, 2) void lstm_layer1_fwd(
    const float* __restrict__ w_ih,   // [2][G][128]  (dir 0)
    const float* __restrict__ w_hh,   // [2][G][64]
    const float* __restrict__ b_ih,
    const float* __restrict__ b_hh)
{
    const int tid  = threadIdx.x;
    const int grp  = tid >> 8;        // 0: k=0..95, 1: k=96..191 (wave-uniform)
    const int gate = tid & 255;
    const int b0   = blockIdx.x * 4;

    __shared__ __align__(16) float x_lds[2][4][128];  // double-buffered
    __shared__ __align__(16) float h_lds[4][HH];
    __shared__ __align__(16) float part[2][4][GG];
    __shared__ __align__(16) float gact[4][GG];

    float4 w0, w1, w2, w3, w4, w5, w6, w7, w8, w9, w10, w11,
           w12, w13, w14, w15, w16, w17, w18, w19, w20, w21, w22, w23;
    if (grp == 0) {
        const float4* p = (const float4*)(w_ih + (size_t)gate * 128);
        w0 = p[0];  w1 = p[1];  w2 = p[2];  w3 = p[3];  w4 = p[4];  w5 = p[5];
        w6 = p[6];  w7 = p[7];  w8 = p[8];  w9 = p[9];  w10 = p[10]; w11 = p[11];
        w12 = p[12]; w13 = p[13]; w14 = p[14]; w15 = p[15]; w16 = p[16]; w17 = p[17];
        w18 = p[18]; w19 = p[19]; w20 = p[20]; w21 = p[21]; w22 = p[22]; w23 = p[23];
    } else {
        const float4* p = (const float4*)(w_ih + (size_t)gate * 128 + 96);
        w0 = p[0]; w1 = p[1]; w2 = p[2]; w3 = p[3];
        w4 = p[4]; w5 = p[5]; w6 = p[6]; w7 = p[7];
        const float4* q = (const float4*)(w_hh + (size_t)gate * HH);
        w8 = q[0];  w9 = q[1];  w10 = q[2]; w11 = q[3]; w12 = q[4]; w13 = q[5];
        w14 = q[6]; w15 = q[7]; w16 = q[8]; w17 = q[9]; w18 = q[10]; w19 = q[11];
        w20 = q[12]; w21 = q[13]; w22 = q[14]; w23 = q[15];
    }
    const float bias = (grp == 0) ? (b_ih[gate] + b_hh[gate]) : 0.0f;

    if (tid < 256) h_lds[tid >> 6][tid & 63] = 0.0f;
    float c_reg = 0.0f;
    const int cb = tid >> 6, cj = tid & 63;     // valid when tid < 256
    const int sb = tid >> 7, sc = tid & 127;    // staging role (all 512)

    x_lds[0][sb][sc] = g_h1[((size_t)0 * BB + (b0 + sb)) * 128 + sc];

    for (int t = 0; t < TT; ++t) {
        __syncthreads();   // [A] x_lds[t&1] + h_lds ready

        PIN(w0); PIN(w1); PIN(w2); PIN(w3); PIN(w4); PIN(w5);
        PIN(w6); PIN(w7); PIN(w8); PIN(w9); PIN(w10); PIN(w11);
        PIN(w12); PIN(w13); PIN(w14); PIN(w15); PIN(w16); PIN(w17);
        PIN(w18); PIN(w19); PIN(w20); PIN(w21); PIN(w22); PIN(w23);

        float xpre = 0.0f;
        if (t + 1 < TT)
            xpre = g_h1[((size_t)(t + 1) * BB + (b0 + sb)) * 128 + sc];

        const float4* xb0 = (const float4*)x_lds[t & 1][0];
        const float4* xb1 = (const float4*)x_lds[t & 1][1];
        const float4* xb2 = (const float4*)x_lds[t & 1][2];
        const float4* xb3 = (const float4*)x_lds[t & 1][3];
        const float4* hb0 = (const float4*)h_lds[0];
        const float4* hb1 = (const float4*)h_lds[1];
        const float4* hb2 = (const float4*)h_lds[2];
        const float4* hb3 = (const float4*)h_lds[3];

        float acc0 = bias, acc1 = bias, acc2 = bias, acc3 = bias;
        if (grp == 0) {
            MAC4(w0, xb0, xb1, xb2, xb3, 0);   MAC4(w1, xb0, xb1, xb2, xb3, 1);
            MAC4(w2, xb0, xb1, xb2, xb3, 2);   MAC4(w3, xb0, xb1, xb2, xb3, 3);
            MAC4(w4, xb0, xb1, xb2, xb3, 4);   MAC4(w5, xb0, xb1, xb2, xb3, 5);
            MAC4(w6, xb0, xb1, xb2, xb3, 6);   MAC4(w7, xb0, xb1, xb2, xb3, 7);
            MAC4(w8, xb0, xb1, xb2, xb3, 8);   MAC4(w9, xb0, xb1, xb2, xb3, 9);
            MAC4(w10, xb0, xb1, xb2, xb3, 10); MAC4(w11, xb0, xb1, xb2, xb3, 11);
            MAC4(w12, xb0, xb1, xb2, xb3, 12); MAC4(w13, xb0, xb1, xb2, xb3, 13);
            MAC4(w14, xb0, xb1, xb2, xb3, 14); MAC4(w15, xb0, xb1, xb2, xb3, 15);
            MAC4(w16, xb0, xb1, xb2, xb3, 16); MAC4(w17, xb0, xb1, xb2, xb3, 17);
            MAC4(w18, xb0, xb1, xb2, xb3, 18); MAC4(w19, xb0, xb1, xb2, xb3, 19);
            MAC4(w20, xb0, xb1, xb2, xb3, 20); MAC4(w21, xb0, xb1, xb2, xb3, 21);
            MAC4(w22, xb0, xb1, xb2, xb3, 22); MAC4(w23, xb0, xb1, xb2, xb3, 23);
        } else {
            MAC4(w0, xb0, xb1, xb2, xb3, 24);  MAC4(w1, xb0, xb1, xb2, xb3, 25);
            MAC4(w2, xb0, xb1, xb2, xb3, 26);  MAC4(w3, xb0, xb1, xb2, xb3, 27);
            MAC4(w4, xb0, xb1, xb2, xb3, 28);  MAC4(w5, xb0, xb1, xb2, xb3, 29);
            MAC4(w6, xb0, xb1, xb2, xb3, 30);  MAC4(w7, xb0, xb1, xb2, xb3, 31);
            MAC4(w8, hb0, hb1, hb2, hb3, 0);   MAC4(w9, hb0, hb1, hb2, hb3, 1);
            MAC4(w10, hb0, hb1, hb2, hb3, 2);  MAC4(w11, hb0, hb1, hb2, hb3, 3);
            MAC4(w12, hb0, hb1, hb2, hb3, 4);  MAC4(w13, hb0, hb1, hb2, hb3, 5);
            MAC4(w14, hb0, hb1, hb2, hb3, 6);  MAC4(w15, hb0, hb1, hb2, hb3, 7);
            MAC4(w16, hb0, hb1, hb2, hb3, 8);  MAC4(w17, hb0, hb1, hb2, hb3, 9);
            MAC4(w18, hb0, hb1, hb2, hb3, 10); MAC4(w19, hb0, hb1, hb2, hb3, 11);
            MAC4(w20, hb0, hb1, hb2, hb3, 12); MAC4(w21, hb0, hb1, hb2, hb3, 13);
            MAC4(w22, hb0, hb1, hb2, hb3, 14); MAC4(w23, hb0, hb1, hb2, hb3, 15);
        }
        part[grp][0][gate] = acc0;
        part[grp][1][gate] = acc1;
        part[grp][2][gate] = acc2;
        part[grp][3][gate] = acc3;
        __syncthreads();   // [B] partials ready; x_lds/h_lds reads done

        {
            const bool is_g = (gate >= 128) && (gate < 192);
#pragma unroll
            for (int bb = 0; bb < 2; ++bb) {
                int b = grp * 2 + bb;
                float sgt = part[0][b][gate] + part[1][b][gate];
                gact[b][gate] = is_g ? ftanh(sgt) : fsigm(sgt);
            }
        }
        __syncthreads();   // [C] gact ready

        if (t + 1 < TT) x_lds[(t + 1) & 1][sb][sc] = xpre;

        if (tid < 256) {
            float ig = gact[cb][cj];
            float fg = gact[cb][HH + cj];
            float gg = gact[cb][2 * HH + cj];
            float og = gact[cb][3 * HH + cj];
            c_reg = fg * c_reg + ig * gg;
            float h = og * ftanh(c_reg);
            h_lds[cb][cj] = h;
            if (t == TT - 1) g_hf[(size_t)(b0 + cb) * HH + cj] = h;
        }
    }
}

// ---------------------------------------------------------------------------
// Layer 1 backward single step (zero state on h1[T-1]) + FC head.
// 256 blocks x 256 threads. Runs once; weight residency irrelevant.
// ---------------------------------------------------------------------------
__global__ __launch_bounds__(256, 2) void lstm_final(
    const float* __restrict__ w_ih,   // [2][G][128] (dir 1)
    const float* __restrict__ b_ih,
    const float* __restrict__ b_hh,
    const float* __restrict__ fc_w,   // [2][128]
    const float* __restrict__ fc_b,   // [2]
    float* __restrict__ out)          // [B][2]
{
    const int tid = threadIdx.x;
    const int b0  = blockIdx.x * 4;

    __shared__ __align__(16) float x_lds[4][128];
    __shared__ __align__(16) float gact[4][GG];
    __shared__ __align__(16) float last[4][128];

#pragma unroll
    for (int r = 0; r < 2; ++r) {
        int idx = tid + r * 256;
        int b = idx >> 7, col = idx & 127;
        x_lds[b][col] = g_h1[((size_t)(TT - 1) * BB + (b0 + b)) * 128 + col];
    }

    const float4* p = (const float4*)(w_ih + ((size_t)GG + tid) * 128);
    float4 w0 = p[0],  w1 = p[1],  w2 = p[2],  w3 = p[3],  w4 = p[4],  w5 = p[5],
           w6 = p[6],  w7 = p[7],  w8 = p[8],  w9 = p[9],  w10 = p[10], w11 = p[11],
           w12 = p[12], w13 = p[13], w14 = p[14], w15 = p[15], w16 = p[16], w17 = p[17],
           w18 = p[18], w19 = p[19], w20 = p[20], w21 = p[21], w22 = p[22], w23 = p[23],
           w24 = p[24], w25 = p[25], w26 = p[26], w27 = p[27], w28 = p[28], w29 = p[29],
           w30 = p[30], w31 = p[31];
    const float bias = b_ih[GG + tid] + b_hh[GG + tid];
    __syncthreads();

    const float4* xb0 = (const float4*)x_lds[0];
    const float4* xb1 = (const float4*)x_lds[1];
    const float4* xb2 = (const float4*)x_lds[2];
    const float4* xb3 = (const float4*)x_lds[3];

    float acc0 = bias, acc1 = bias, acc2 = bias, acc3 = bias;
    MAC4(w0, xb0, xb1, xb2, xb3, 0);   MAC4(w1, xb0, xb1, xb2, xb3, 1);
    MAC4(w2, xb0, xb1, xb2, xb3, 2);   MAC4(w3, xb0, xb1, xb2, xb3, 3);
    MAC4(w4, xb0, xb1, xb2, xb3, 4);   MAC4(w5, xb0, xb1, xb2, xb3, 5);
    MAC4(w6, xb0, xb1, xb2, xb3, 6);   MAC4(w7, xb0, xb1, xb2, xb3, 7);
    MAC4(w8, xb0, xb1, xb2, xb3, 8);   MAC4(w9, xb0, xb1, xb2, xb3, 9);
    MAC4(w10, xb0, xb1, xb2, xb3, 10); MAC4(w11, xb0, xb1, xb2, xb3, 11);
    MAC4(w12, xb0, xb1, xb2, xb3, 12); MAC4(w13, xb0, xb1, xb2, xb3, 13);
    MAC4(w14, xb0, xb1, xb2, xb3, 14); MAC4(w15, xb0, xb1, xb2, xb3, 15);
    MAC4(w16, xb0, xb1, xb2, xb3, 16); MAC4(w17, xb0, xb1, xb2, xb3, 17);
    MAC4(w18, xb0, xb1, xb2, xb3, 18); MAC4(w19, xb0, xb1, xb2, xb3, 19);
    MAC4(w20, xb0, xb1, xb2, xb3, 20); MAC4(w21, xb0, xb1, xb2, xb3, 21);
    MAC4(w22, xb0, xb1, xb2, xb3, 22); MAC4(w23, xb0, xb1, xb2, xb3, 23);
    MAC4(w24, xb0, xb1, xb2, xb3, 24); MAC4(w25, xb0, xb1, xb2, xb3, 25);
    MAC4(w26, xb0, xb1, xb2, xb3, 26); MAC4(w27, xb0, xb1, xb2, xb3, 27);
    MAC4(w28, xb0, xb1, xb2, xb3, 28); MAC4(w29, xb0, xb1, xb2, xb3, 29);
    MAC4(w30, xb0, xb1, xb2, xb3, 30); MAC4(w31, xb0, xb1, xb2, xb3, 31);

    const bool is_g = ((tid >> 6) == 2);
    gact[0][tid] = is_g ? ftanh(acc0) : fsigm(acc0);
    gact[1][tid] = is_g ? ftanh(acc1) : fsigm(acc1);
    gact[2][tid] = is_g ? ftanh(acc2) : fsigm(acc2);
    gact[3][tid] = is_g ? ftanh(acc3) : fsigm(acc3);
    __syncthreads();

    {
        const int cb = tid >> 6, cj = tid & 63;
        float ig = gact[cb][cj];
        float gg = gact[cb][2 * HH + cj];
        float og = gact[cb][3 * HH + cj];
        float c = ig * gg;
        float h = og * ftanh(c);
        last[cb][HH + cj] = h;
        last[cb][cj] = g_hf[(size_t)(b0 + cb) * HH + cj];
    }
    __syncthreads();

    if (tid < 8) {
        int b = tid >> 1, o = tid & 1;
        float a = fc_b[o];
#pragma unroll
        for (int j = 0; j < 128; ++j) a += fc_w[o * 128 + j] * last[b][j];
        out[(size_t)(b0 + b) * 2 + o] = a;
    }
}

extern "C" void kernel_launch(void* const* d_in, const int* in_sizes, int n_in,
                              void* d_out, int out_size, void* d_ws, size_t ws_size,
                              hipStream_t stream) {
    const float* x     = (const float*)d_in[0];
    const float* w_ih0 = (const float*)d_in[1];
    const float* w_hh0 = (const float*)d_in[2];
    const float* b_ih0 = (const float*)d_in[3];
    const float* b_hh0 = (const float*)d_in[4];
    const float* w_ih1 = (const float*)d_in[5];
    const float* w_hh1 = (const float*)d_in[6];
    const float* b_ih1 = (const float*)d_in[7];
    const float* b_hh1 = (const float*)d_in[8];
    const float* fc_w  = (const float*)d_in[9];
    const float* fc_b  = (const float*)d_in[10];
    float* out = (float*)d_out;

    lstm_layer0<<<512, 256, 0, stream>>>(x, w_ih0, w_hh0, b_ih0, b_hh0);
    lstm_layer1_fwd<<<256, 512, 0, stream>>>(w_ih1, w_hh1, b_ih1, b_hh1);
    lstm_final<<<256, 256, 0, stream>>>(w_ih1, b_ih1, b_hh1, fc_w, fc_b, out);
}

// Round 7
// 7685.531 us; speedup vs baseline: 3.3066x; 2.8665x over previous
//
#include <hip/hip_runtime.h>

#define TT 512
#define BB 1024
#define FF 32
#define HH 64
#define GG 256   // 4*H gates per direction

// Static device scratch (ws_size-independent). Fully overwritten every call.
__device__ float g_h1[(size_t)TT * BB * 2 * HH];   // [T][B][128] layer-1 input, 256 MB
__device__ float g_pre1[(size_t)TT * BB * GG];     // [T][B][256] layer-1 fwd pre-gates, 537 MB
__device__ float g_hf[(size_t)BB * HH];            // [B][64] final fwd h of layer1

__device__ __forceinline__ float fsigm(float x) {
    float e = __builtin_amdgcn_exp2f(x * -1.44269504088896f);
    return __builtin_amdgcn_rcpf(1.0f + e);
}
__device__ __forceinline__ float ftanh(float x) {
    float e = __builtin_amdgcn_exp2f(x * -2.88539008177793f);
    return 2.0f * __builtin_amdgcn_rcpf(1.0f + e) - 1.0f;
}
// Wave-uniform broadcast via v_readlane (VALU->SGPR, zero LDS-pipe cost).
__device__ __forceinline__ float rlane(float v, int l) {
    return __int_as_float(__builtin_amdgcn_readlane(__float_as_int(v), l));
}

// h-matvec step: acc_b += sum_c h[b][4*J4+c] * w[gate][4*J4+c].
// h_flat[b*64+j] staged as lane (b*16+j4) component c of hs0..hs3.
#define HM(J4, WQ) do{                                                        \
    acc0 += rlane(hs0,(J4)   )*(WQ).x + rlane(hs1,(J4)   )*(WQ).y             \
          + rlane(hs2,(J4)   )*(WQ).z + rlane(hs3,(J4)   )*(WQ).w;            \
    acc1 += rlane(hs0,16+(J4))*(WQ).x + rlane(hs1,16+(J4))*(WQ).y             \
          + rlane(hs2,16+(J4))*(WQ).z + rlane(hs3,16+(J4))*(WQ).w;            \
    acc2 += rlane(hs0,32+(J4))*(WQ).x + rlane(hs1,32+(J4))*(WQ).y             \
          + rlane(hs2,32+(J4))*(WQ).z + rlane(hs3,32+(J4))*(WQ).w;            \
    acc3 += rlane(hs0,48+(J4))*(WQ).x + rlane(hs1,48+(J4))*(WQ).y             \
          + rlane(hs2,48+(J4))*(WQ).z + rlane(hs3,48+(J4))*(WQ).w;            \
}while(0)

// x-matvec step: x_flat[b*32+f] staged as lane (b*8+f4) component c of xq0..3.
#define XM(F4, WIQ) do{                                                       \
    acc0 += rlane(xq0,(F4)   )*(WIQ).x + rlane(xq1,(F4)   )*(WIQ).y           \
          + rlane(xq2,(F4)   )*(WIQ).z + rlane(xq3,(F4)   )*(WIQ).w;          \
    acc1 += rlane(xq0, 8+(F4))*(WIQ).x + rlane(xq1, 8+(F4))*(WIQ).y           \
          + rlane(xq2, 8+(F4))*(WIQ).z + rlane(xq3, 8+(F4))*(WIQ).w;          \
    acc2 += rlane(xq0,16+(F4))*(WIQ).x + rlane(xq1,16+(F4))*(WIQ).y           \
          + rlane(xq2,16+(F4))*(WIQ).z + rlane(xq3,16+(F4))*(WIQ).w;          \
    acc3 += rlane(xq0,24+(F4))*(WIQ).x + rlane(xq1,24+(F4))*(WIQ).y           \
          + rlane(xq2,24+(F4))*(WIQ).z + rlane(xq3,24+(F4))*(WIQ).w;          \
}while(0)

// ---------------------------------------------------------------------------
// Layer 0 (both directions), fused scan. 512 blocks (dir=bid&1, 4 batches)
// x 256 threads (thread = gate). w_hh quads 0..11 in LDS (48 KB), quads
// 12..15 + w_ih (8 quads) in regs (48 floats — under the 128-VGPR cap).
// h and x broadcast via readlane from per-lane staged registers.
// ---------------------------------------------------------------------------
__global__ __launch_bounds__(256, 2) void lstm_layer0(
    const float* __restrict__ x,      // [B][T][F]
    const float* __restrict__ w_ih,   // [2][G][F]
    const float* __restrict__ w_hh,   // [2][G][H]
    const float* __restrict__ b_ih,   // [2][G]
    const float* __restrict__ b_hh)   // [2][G]
{
    const int tid  = threadIdx.x;
    const int dir  = blockIdx.x & 1;
    const int b0   = (blockIdx.x >> 1) * 4;
    const int lane = tid & 63;

    __shared__ __align__(16) float4 wlds[12 * 256];   // [j4][gate], 48 KB
    __shared__ float gact[4][GG];                     // [b][gate]
    __shared__ __align__(16) float hbuf[256];         // h_flat[b*64+j]

    const float4* wsrc = (const float4*)(w_hh + (size_t)dir * GG * HH) + (size_t)tid * 16;
#pragma unroll
    for (int j4 = 0; j4 < 12; ++j4) wlds[j4 * 256 + tid] = wsrc[j4];
    float4 wr0 = wsrc[12], wr1 = wsrc[13], wr2 = wsrc[14], wr3 = wsrc[15];

    const float4* wisrc = (const float4*)(w_ih + ((size_t)dir * GG + tid) * FF);
    float4 wi0 = wisrc[0], wi1 = wisrc[1], wi2 = wisrc[2], wi3 = wisrc[3],
           wi4 = wisrc[4], wi5 = wisrc[5], wi6 = wisrc[6], wi7 = wisrc[7];
    const float bias = b_ih[dir * GG + tid] + b_hh[dir * GG + tid];
    __syncthreads();   // wlds ready

    float c_reg = 0.f;
    float hs0 = 0.f, hs1 = 0.f, hs2 = 0.f, hs3 = 0.f;   // staged h (zero state)
    const int cb = tid >> 6, cj = tid & 63;             // cell role
    const bool is_g = (cb == 2);                        // wave-uniform

    // x staging: lane L<32 holds x_flat[4L..4L+3]; quad q=L: b=q>>3, f4=q&7
    const int xb = (lane & 31) >> 3, xf4 = lane & 7;
    float xq0, xq1, xq2, xq3;
    {
        int t0 = dir ? (TT - 1) : 0;
        float4 v = *(const float4*)(x + ((size_t)(b0 + xb) * TT + t0) * FF + xf4 * 4);
        xq0 = v.x; xq1 = v.y; xq2 = v.z; xq3 = v.w;
    }

    for (int s = 0; s < TT; ++s) {
        const int t = dir ? (TT - 1 - s) : s;
        // prefetch next step's x quad (hidden behind the MAC chain)
        float xn0 = 0.f, xn1 = 0.f, xn2 = 0.f, xn3 = 0.f;
        if (s + 1 < TT) {
            int tn = dir ? (TT - 2 - s) : (s + 1);
            float4 v = *(const float4*)(x + ((size_t)(b0 + xb) * TT + tn) * FF + xf4 * 4);
            xn0 = v.x; xn1 = v.y; xn2 = v.z; xn3 = v.w;
        }

        float acc0 = bias, acc1 = bias, acc2 = bias, acc3 = bias;
#pragma unroll
        for (int j4 = 0; j4 < 12; ++j4) {
            float4 wq = wlds[j4 * 256 + tid];   // conflict-free (lane=gate)
            HM(j4, wq);
        }
        HM(12, wr0); HM(13, wr1); HM(14, wr2); HM(15, wr3);
        XM(0, wi0); XM(1, wi1); XM(2, wi2); XM(3, wi3);
        XM(4, wi4); XM(5, wi5); XM(6, wi6); XM(7, wi7);

        gact[0][tid] = is_g ? ftanh(acc0) : fsigm(acc0);
        gact[1][tid] = is_g ? ftanh(acc1) : fsigm(acc1);
        gact[2][tid] = is_g ? ftanh(acc2) : fsigm(acc2);
        gact[3][tid] = is_g ? ftanh(acc3) : fsigm(acc3);
        __syncthreads();   // gact ready (hbuf stage-reads of prev step done)

        {   // cell update: thread -> (cb, cj)
            float ig = gact[cb][cj];
            float fg = gact[cb][HH + cj];
            float gg = gact[cb][2 * HH + cj];
            float og = gact[cb][3 * HH + cj];
            c_reg = fg * c_reg + ig * gg;
            float h = og * ftanh(c_reg);
            hbuf[tid] = h;   // tid == cb*64+cj
            g_h1[((size_t)t * BB + (b0 + cb)) * (2 * HH) + dir * HH + cj] = h;
        }
        __syncthreads();   // hbuf ready

        float4 hv = ((const float4*)hbuf)[lane];
        hs0 = hv.x; hs1 = hv.y; hs2 = hv.z; hs3 = hv.w;
        xq0 = xn0; xq1 = xn1; xq2 = xn2; xq3 = xn3;
    }
}

// ---------------------------------------------------------------------------
// Layer-1 forward input pre-gates (time-parallel GEMM, no recurrence):
// pre1[t][b][gate] = h1[t][b][:] . w_ih1[0][gate][:] + b_ih1[0]+b_hh1[0].
// 2048 blocks x 128 thr: b = bid>>1, gate-half = bid&1. Weights in 64 KB LDS,
// h1 rows via wave-uniform loads (scalar path), 8 t's per accumulator pass.
// ---------------------------------------------------------------------------
__global__ __launch_bounds__(128, 2) void pre_gemm1(
    const float* __restrict__ w_ih,   // [2][G][128] (dir 0 used)
    const float* __restrict__ b_ih,
    const float* __restrict__ b_hh)
{
    const int tid  = threadIdx.x;          // 0..127
    const int b    = blockIdx.x >> 1;
    const int gate = (blockIdx.x & 1) * 128 + tid;

    __shared__ __align__(16) float4 w4[32 * 128];   // [kq][gate-local], 64 KB
    const float4* wsrc = (const float4*)w_ih + (size_t)gate * 32;
#pragma unroll
    for (int kq = 0; kq < 32; ++kq) w4[kq * 128 + tid] = wsrc[kq];
    const float bias = b_ih[gate] + b_hh[gate];
    __syncthreads();

    const size_t STRD = (size_t)BB * 128;   // h1 t-stride (floats)
    for (int tc = 0; tc < 64; ++tc) {
        const float* hrow = g_h1 + ((size_t)(tc * 8) * BB + b) * 128;
        float a0 = bias, a1 = bias, a2 = bias, a3 = bias,
              a4 = bias, a5 = bias, a6 = bias, a7 = bias;
#pragma unroll
        for (int kq = 0; kq < 32; ++kq) {
            float4 wq = w4[kq * 128 + tid];
            const float* hp = hrow + kq * 4;
            float4 q;
            q = *(const float4*)(hp + 0 * STRD); a0 += q.x*wq.x + q.y*wq.y + q.z*wq.z + q.w*wq.w;
            q = *(const float4*)(hp + 1 * STRD); a1 += q.x*wq.x + q.y*wq.y + q.z*wq.z + q.w*wq.w;
            q = *(const float4*)(hp + 2 * STRD); a2 += q.x*wq.x + q.y*wq.y + q.z*wq.z + q.w*wq.w;
            q = *(const float4*)(hp + 3 * STRD); a3 += q.x*wq.x + q.y*wq.y + q.z*wq.z + q.w*wq.w;
            q = *(const float4*)(hp + 4 * STRD); a4 += q.x*wq.x + q.y*wq.y + q.z*wq.z + q.w*wq.w;
            q = *(const float4*)(hp + 5 * STRD); a5 += q.x*wq.x + q.y*wq.y + q.z*wq.z + q.w*wq.w;
            q = *(const float4*)(hp + 6 * STRD); a6 += q.x*wq.x + q.y*wq.y + q.z*wq.z + q.w*wq.w;
            q = *(const float4*)(hp + 7 * STRD); a7 += q.x*wq.x + q.y*wq.y + q.z*wq.z + q.w*wq.w;
        }
        float* op = g_pre1 + ((size_t)(tc * 8) * BB + b) * GG + gate;
        const size_t OS = (size_t)BB * GG;
        op[0] = a0; op[1 * OS] = a1; op[2 * OS] = a2; op[3 * OS] = a3;
        op[4 * OS] = a4; op[5 * OS] = a5; op[6 * OS] = a6; op[7 * OS] = a7;
    }
}

// ---------------------------------------------------------------------------
// Layer 1 forward scan: only the K=64 recurrent matvec + cell; pre-gates
// streamed from g_pre1. 256 blocks x 256 thr, 4 batches/block.
// ---------------------------------------------------------------------------
__global__ __launch_bounds__(256, 2) void lstm_layer1_fwd(
    const float* __restrict__ w_hh)   // [2][G][64] (dir 0 used)
{
    const int tid  = threadIdx.x;
    const int b0   = blockIdx.x * 4;
    const int lane = tid & 63;

    __shared__ __align__(16) float4 wlds[12 * 256];   // 48 KB
    __shared__ float gact[4][GG];
    __shared__ __align__(16) float hbuf[256];

    const float4* wsrc = (const float4*)w_hh + (size_t)tid * 16;
#pragma unroll
    for (int j4 = 0; j4 < 12; ++j4) wlds[j4 * 256 + tid] = wsrc[j4];
    float4 wr0 = wsrc[12], wr1 = wsrc[13], wr2 = wsrc[14], wr3 = wsrc[15];
    __syncthreads();

    float c_reg = 0.f;
    float hs0 = 0.f, hs1 = 0.f, hs2 = 0.f, hs3 = 0.f;
    const int cb = tid >> 6, cj = tid & 63;
    const bool is_g = (cb == 2);

    // pre-gate streams (coalesced: lane = gate), prefetched one step ahead
    float p0 = g_pre1[((size_t)0 * BB + (b0 + 0)) * GG + tid];
    float p1 = g_pre1[((size_t)0 * BB + (b0 + 1)) * GG + tid];
    float p2 = g_pre1[((size_t)0 * BB + (b0 + 2)) * GG + tid];
    float p3 = g_pre1[((size_t)0 * BB + (b0 + 3)) * GG + tid];

    for (int t = 0; t < TT; ++t) {
        float n0 = 0.f, n1 = 0.f, n2 = 0.f, n3 = 0.f;
        if (t + 1 < TT) {
            n0 = g_pre1[((size_t)(t + 1) * BB + (b0 + 0)) * GG + tid];
            n1 = g_pre1[((size_t)(t + 1) * BB + (b0 + 1)) * GG + tid];
            n2 = g_pre1[((size_t)(t + 1) * BB + (b0 + 2)) * GG + tid];
            n3 = g_pre1[((size_t)(t + 1) * BB + (b0 + 3)) * GG + tid];
        }
        float acc0 = p0, acc1 = p1, acc2 = p2, acc3 = p3;
#pragma unroll
        for (int j4 = 0; j4 < 12; ++j4) {
            float4 wq = wlds[j4 * 256 + tid];
            HM(j4, wq);
        }
        HM(12, wr0); HM(13, wr1); HM(14, wr2); HM(15, wr3);

        gact[0][tid] = is_g ? ftanh(acc0) : fsigm(acc0);
        gact[1][tid] = is_g ? ftanh(acc1) : fsigm(acc1);
        gact[2][tid] = is_g ? ftanh(acc2) : fsigm(acc2);
        gact[3][tid] = is_g ? ftanh(acc3) : fsigm(acc3);
        __syncthreads();

        {
            float ig = gact[cb][cj];
            float fg = gact[cb][HH + cj];
            float gg = gact[cb][2 * HH + cj];
            float og = gact[cb][3 * HH + cj];
            c_reg = fg * c_reg + ig * gg;
            float h = og * ftanh(c_reg);
            hbuf[tid] = h;
            if (t == TT - 1) g_hf[(size_t)(b0 + cb) * HH + cj] = h;
        }
        __syncthreads();

        float4 hv = ((const float4*)hbuf)[lane];
        hs0 = hv.x; hs1 = hv.y; hs2 = hv.z; hs3 = hv.w;
        p0 = n0; p1 = n1; p2 = n2; p3 = n3;
    }
}

// ---------------------------------------------------------------------------
// Layer 1 backward single step (zero state on h1[T-1]) + FC head.
// Unchanged from the passing r6 kernel (runs once; cost negligible).
// ---------------------------------------------------------------------------
#define FMAC4(W, P0, P1, P2, P3, K) do{                                   \
    float4 v_;                                                           \
    v_ = (P0)[K]; acc0 += W.x*v_.x; acc0 += W.y*v_.y; acc0 += W.z*v_.z; acc0 += W.w*v_.w; \
    v_ = (P1)[K]; acc1 += W.x*v_.x; acc1 += W.y*v_.y; acc1 += W.z*v_.z; acc1 += W.w*v_.w; \
    v_ = (P2)[K]; acc2 += W.x*v_.x; acc2 += W.y*v_.y; acc2 += W.z*v_.z; acc2 += W.w*v_.w; \
    v_ = (P3)[K]; acc3 += W.x*v_.x; acc3 += W.y*v_.y; acc3 += W.z*v_.z; acc3 += W.w*v_.w; \
}while(0)

__global__ __launch_bounds__(256, 2) void lstm_final(
    const float* __restrict__ w_ih,   // [2][G][128] (dir 1)
    const float* __restrict__ b_ih,
    const float* __restrict__ b_hh,
    const float* __restrict__ fc_w,   // [2][128]
    const float* __restrict__ fc_b,   // [2]
    float* __restrict__ out)          // [B][2]
{
    const int tid = threadIdx.x;
    const int b0  = blockIdx.x * 4;

    __shared__ __align__(16) float x_lds[4][128];
    __shared__ __align__(16) float gact[4][GG];
    __shared__ __align__(16) float last[4][128];

#pragma unroll
    for (int r = 0; r < 2; ++r) {
        int idx = tid + r * 256;
        int b = idx >> 7, col = idx & 127;
        x_lds[b][col] = g_h1[((size_t)(TT - 1) * BB + (b0 + b)) * 128 + col];
    }

    const float4* p = (const float4*)(w_ih + ((size_t)GG + tid) * 128);
    float4 w0 = p[0],  w1 = p[1],  w2 = p[2],  w3 = p[3],  w4 = p[4],  w5 = p[5],
           w6 = p[6],  w7 = p[7],  w8 = p[8],  w9 = p[9],  w10 = p[10], w11 = p[11],
           w12 = p[12], w13 = p[13], w14 = p[14], w15 = p[15], w16 = p[16], w17 = p[17],
           w18 = p[18], w19 = p[19], w20 = p[20], w21 = p[21], w22 = p[22], w23 = p[23],
           w24 = p[24], w25 = p[25], w26 = p[26], w27 = p[27], w28 = p[28], w29 = p[29],
           w30 = p[30], w31 = p[31];
    const float bias = b_ih[GG + tid] + b_hh[GG + tid];
    __syncthreads();

    const float4* xb0 = (const float4*)x_lds[0];
    const float4* xb1 = (const float4*)x_lds[1];
    const float4* xb2 = (const float4*)x_lds[2];
    const float4* xb3 = (const float4*)x_lds[3];

    float acc0 = bias, acc1 = bias, acc2 = bias, acc3 = bias;
    FMAC4(w0, xb0, xb1, xb2, xb3, 0);   FMAC4(w1, xb0, xb1, xb2, xb3, 1);
    FMAC4(w2, xb0, xb1, xb2, xb3, 2);   FMAC4(w3, xb0, xb1, xb2, xb3, 3);
    FMAC4(w4, xb0, xb1, xb2, xb3, 4);   FMAC4(w5, xb0, xb1, xb2, xb3, 5);
    FMAC4(w6, xb0, xb1, xb2, xb3, 6);   FMAC4(w7, xb0, xb1, xb2, xb3, 7);
    FMAC4(w8, xb0, xb1, xb2, xb3, 8);   FMAC4(w9, xb0, xb1, xb2, xb3, 9);
    FMAC4(w10, xb0, xb1, xb2, xb3, 10); FMAC4(w11, xb0, xb1, xb2, xb3, 11);
    FMAC4(w12, xb0, xb1, xb2, xb3, 12); FMAC4(w13, xb0, xb1, xb2, xb3, 13);
    FMAC4(w14, xb0, xb1, xb2, xb3, 14); FMAC4(w15, xb0, xb1, xb2, xb3, 15);
    FMAC4(w16, xb0, xb1, xb2, xb3, 16); FMAC4(w17, xb0, xb1, xb2, xb3, 17);
    FMAC4(w18, xb0, xb1, xb2, xb3, 18); FMAC4(w19, xb0, xb1, xb2, xb3, 19);
    FMAC4(w20, xb0, xb1, xb2, xb3, 20); FMAC4(w21, xb0, xb1, xb2, xb3, 21);
    FMAC4(w22, xb0, xb1, xb2, xb3, 22); FMAC4(w23, xb0, xb1, xb2, xb3, 23);
    FMAC4(w24, xb0, xb1, xb2, xb3, 24); FMAC4(w25, xb0, xb1, xb2, xb3, 25);
    FMAC4(w26, xb0, xb1, xb2, xb3, 26); FMAC4(w27, xb0, xb1, xb2, xb3, 27);
    FMAC4(w28, xb0, xb1, xb2, xb3, 28); FMAC4(w29, xb0, xb1, xb2, xb3, 29);
    FMAC4(w30, xb0, xb1, xb2, xb3, 30); FMAC4(w31, xb0, xb1, xb2, xb3, 31);

    const bool is_g = ((tid >> 6) == 2);
    gact[0][tid] = is_g ? ftanh(acc0) : fsigm(acc0);
    gact[1][tid] = is_g ? ftanh(acc1) : fsigm(acc1);
    gact[2][tid] = is_g ? ftanh(acc2) : fsigm(acc2);
    gact[3][tid] = is_g ? ftanh(acc3) : fsigm(acc3);
    __syncthreads();

    {
        const int cb = tid >> 6, cj = tid & 63;
        float ig = gact[cb][cj];
        float gg = gact[cb][2 * HH + cj];
        float og = gact[cb][3 * HH + cj];
        float c = ig * gg;
        float h = og * ftanh(c);
        last[cb][HH + cj] = h;
        last[cb][cj] = g_hf[(size_t)(b0 + cb) * HH + cj];
    }
    __syncthreads();

    if (tid < 8) {
        int b = tid >> 1, o = tid & 1;
        float a = fc_b[o];
#pragma unroll
        for (int j = 0; j < 128; ++j) a += fc_w[o * 128 + j] * last[b][j];
        out[(size_t)(b0 + b) * 2 + o] = a;
    }
}

extern "C" void kernel_launch(void* const* d_in, const int* in_sizes, int n_in,
                              void* d_out, int out_size, void* d_ws, size_t ws_size,
                              hipStream_t stream) {
    const float* x     = (const float*)d_in[0];
    const float* w_ih0 = (const float*)d_in[1];
    const float* w_hh0 = (const float*)d_in[2];
    const float* b_ih0 = (const float*)d_in[3];
    const float* b_hh0 = (const float*)d_in[4];
    const float* w_ih1 = (const float*)d_in[5];
    const float* w_hh1 = (const float*)d_in[6];
    const float* b_ih1 = (const float*)d_in[7];
    const float* b_hh1 = (const float*)d_in[8];
    const float* fc_w  = (const float*)d_in[9];
    const float* fc_b  = (const float*)d_in[10];
    float* out = (float*)d_out;

    lstm_layer0<<<512, 256, 0, stream>>>(x, w_ih0, w_hh0, b_ih0, b_hh0);
    pre_gemm1<<<2048, 128, 0, stream>>>(w_ih1, b_ih1, b_hh1);
    lstm_layer1_fwd<<<256, 256, 0, stream>>>(w_hh1);
    lstm_final<<<256, 256, 0, stream>>>(w_ih1, b_ih1, b_hh1, fc_w, fc_b, out);
}

// Round 8
// 7093.538 us; speedup vs baseline: 3.5826x; 1.0835x over previous
//
#include <hip/hip_runtime.h>

#define TT 512
#define BB 1024
#define FF 32
#define HH 64
#define GG 256   // 4*H gates per direction

// Static device scratch (ws_size-independent). Fully overwritten every call.
__device__ float g_h1[(size_t)TT * BB * 2 * HH];   // [T][B][128] layer-1 input, 256 MB
__device__ float g_pre0[(size_t)2 * TT * BB * GG]; // [dir][T][B][256] layer-0 pre-gates, 1.07 GB
__device__ float g_pre1[(size_t)TT * BB * GG];     // [T][B][256] layer-1 fwd pre-gates, 537 MB
__device__ float g_hf[(size_t)BB * HH];            // [B][64] final fwd h of layer1

__device__ __forceinline__ float fsigm(float x) {
    float e = __builtin_amdgcn_exp2f(x * -1.44269504088896f);
    return __builtin_amdgcn_rcpf(1.0f + e);
}
__device__ __forceinline__ float ftanh(float x) {
    float e = __builtin_amdgcn_exp2f(x * -2.88539008177793f);
    return 2.0f * __builtin_amdgcn_rcpf(1.0f + e) - 1.0f;
}
// Wave-uniform broadcast via v_readlane (VALU->SGPR, zero LDS-pipe cost).
__device__ __forceinline__ float rlane(float v, int l) {
    return __int_as_float(__builtin_amdgcn_readlane(__float_as_int(v), l));
}

// h-matvec step: acc_b += sum_c h[b][4*J4+c] * w[gate][4*J4+c].
// h_flat[b*64+j] staged as lane (b*16+j4) component c of hs0..hs3.
#define HM(J4, WQ) do{                                                        \
    acc0 += rlane(hs0,(J4)   )*(WQ).x + rlane(hs1,(J4)   )*(WQ).y             \
          + rlane(hs2,(J4)   )*(WQ).z + rlane(hs3,(J4)   )*(WQ).w;            \
    acc1 += rlane(hs0,16+(J4))*(WQ).x + rlane(hs1,16+(J4))*(WQ).y             \
          + rlane(hs2,16+(J4))*(WQ).z + rlane(hs3,16+(J4))*(WQ).w;            \
    acc2 += rlane(hs0,32+(J4))*(WQ).x + rlane(hs1,32+(J4))*(WQ).y             \
          + rlane(hs2,32+(J4))*(WQ).z + rlane(hs3,32+(J4))*(WQ).w;            \
    acc3 += rlane(hs0,48+(J4))*(WQ).x + rlane(hs1,48+(J4))*(WQ).y             \
          + rlane(hs2,48+(J4))*(WQ).z + rlane(hs3,48+(J4))*(WQ).w;            \
}while(0)

// ---------------------------------------------------------------------------
// Layer-0 input pre-gates (time-parallel, no recurrence):
// pre0[dir][t][b][gate] = x[b][t][:] . w_ih0[dir][gate][:] + b_ih0 + b_hh0.
// 2048 blocks (b = bid>>1, dir = bid&1) x 256 thr (thread = gate).
// Weights in 32 KB LDS -> 4 blocks/CU, x rows via wave-uniform loads.
// ---------------------------------------------------------------------------
__global__ __launch_bounds__(256, 4) void pre_gemm0(
    const float* __restrict__ x,      // [B][T][F]
    const float* __restrict__ w_ih,   // [2][G][F]
    const float* __restrict__ b_ih,
    const float* __restrict__ b_hh)
{
    const int tid = threadIdx.x;          // gate
    const int b   = blockIdx.x >> 1;
    const int dir = blockIdx.x & 1;

    __shared__ __align__(16) float4 w4[8 * 256];   // [kq][gate], 32 KB
    const float4* wsrc = (const float4*)(w_ih + ((size_t)dir * GG + tid) * FF);
#pragma unroll
    for (int kq = 0; kq < 8; ++kq) w4[kq * 256 + tid] = wsrc[kq];
    const float bias = b_ih[dir * GG + tid] + b_hh[dir * GG + tid];
    __syncthreads();

    const size_t OS = (size_t)BB * GG;
    for (int tc = 0; tc < 64; ++tc) {
        const float* xrow = x + ((size_t)b * TT + tc * 8) * FF;
        float a0 = bias, a1 = bias, a2 = bias, a3 = bias,
              a4 = bias, a5 = bias, a6 = bias, a7 = bias;
#pragma unroll
        for (int kq = 0; kq < 8; ++kq) {
            float4 wq = w4[kq * 256 + tid];
            const float* xp = xrow + kq * 4;
            float4 q;
            q = *(const float4*)(xp + 0 * FF); a0 += q.x*wq.x + q.y*wq.y + q.z*wq.z + q.w*wq.w;
            q = *(const float4*)(xp + 1 * FF); a1 += q.x*wq.x + q.y*wq.y + q.z*wq.z + q.w*wq.w;
            q = *(const float4*)(xp + 2 * FF); a2 += q.x*wq.x + q.y*wq.y + q.z*wq.z + q.w*wq.w;
            q = *(const float4*)(xp + 3 * FF); a3 += q.x*wq.x + q.y*wq.y + q.z*wq.z + q.w*wq.w;
            q = *(const float4*)(xp + 4 * FF); a4 += q.x*wq.x + q.y*wq.y + q.z*wq.z + q.w*wq.w;
            q = *(const float4*)(xp + 5 * FF); a5 += q.x*wq.x + q.y*wq.y + q.z*wq.z + q.w*wq.w;
            q = *(const float4*)(xp + 6 * FF); a6 += q.x*wq.x + q.y*wq.y + q.z*wq.z + q.w*wq.w;
            q = *(const float4*)(xp + 7 * FF); a7 += q.x*wq.x + q.y*wq.y + q.z*wq.z + q.w*wq.w;
        }
        float* op = g_pre0 + (((size_t)dir * TT + tc * 8) * BB + b) * GG + tid;
        op[0] = a0; op[1 * OS] = a1; op[2 * OS] = a2; op[3 * OS] = a3;
        op[4 * OS] = a4; op[5 * OS] = a5; op[6 * OS] = a6; op[7 * OS] = a7;
    }
}

// ---------------------------------------------------------------------------
// Layer 0 recurrent-only scan (clone of the proven r7 layer-1 scan).
// 512 blocks (dir = bid&1, 4 batches) x 256 thr (thread = gate).
// w_hh quads 0..11 in 48 KB LDS, 12..15 in regs; pre-gates from g_pre0.
// ---------------------------------------------------------------------------
__global__ __launch_bounds__(256, 2) void lstm_layer0_scan(
    const float* __restrict__ w_hh)   // [2][G][64]
{
    const int tid  = threadIdx.x;
    const int dir  = blockIdx.x & 1;
    const int b0   = (blockIdx.x >> 1) * 4;
    const int lane = tid & 63;

    __shared__ __align__(16) float4 wlds[12 * 256];   // 48 KB
    __shared__ float gact[4][GG];
    __shared__ __align__(16) float hbuf[256];

    const float4* wsrc = (const float4*)(w_hh + (size_t)dir * GG * HH) + (size_t)tid * 16;
#pragma unroll
    for (int j4 = 0; j4 < 12; ++j4) wlds[j4 * 256 + tid] = wsrc[j4];
    float4 wr0 = wsrc[12], wr1 = wsrc[13], wr2 = wsrc[14], wr3 = wsrc[15];
    __syncthreads();

    float c_reg = 0.f;
    float hs0 = 0.f, hs1 = 0.f, hs2 = 0.f, hs3 = 0.f;
    const int cb = tid >> 6, cj = tid & 63;
    const bool is_g = (cb == 2);

    const size_t DOFF = (size_t)dir * TT;
    int t0 = dir ? (TT - 1) : 0;
    float p0 = g_pre0[((DOFF + t0) * BB + (b0 + 0)) * GG + tid];
    float p1 = g_pre0[((DOFF + t0) * BB + (b0 + 1)) * GG + tid];
    float p2 = g_pre0[((DOFF + t0) * BB + (b0 + 2)) * GG + tid];
    float p3 = g_pre0[((DOFF + t0) * BB + (b0 + 3)) * GG + tid];

    for (int s = 0; s < TT; ++s) {
        const int t = dir ? (TT - 1 - s) : s;
        float n0 = 0.f, n1 = 0.f, n2 = 0.f, n3 = 0.f;
        if (s + 1 < TT) {
            int tn = dir ? (TT - 2 - s) : (s + 1);
            n0 = g_pre0[((DOFF + tn) * BB + (b0 + 0)) * GG + tid];
            n1 = g_pre0[((DOFF + tn) * BB + (b0 + 1)) * GG + tid];
            n2 = g_pre0[((DOFF + tn) * BB + (b0 + 2)) * GG + tid];
            n3 = g_pre0[((DOFF + tn) * BB + (b0 + 3)) * GG + tid];
        }
        float acc0 = p0, acc1 = p1, acc2 = p2, acc3 = p3;
#pragma unroll
        for (int j4 = 0; j4 < 12; ++j4) {
            float4 wq = wlds[j4 * 256 + tid];
            HM(j4, wq);
        }
        HM(12, wr0); HM(13, wr1); HM(14, wr2); HM(15, wr3);

        gact[0][tid] = is_g ? ftanh(acc0) : fsigm(acc0);
        gact[1][tid] = is_g ? ftanh(acc1) : fsigm(acc1);
        gact[2][tid] = is_g ? ftanh(acc2) : fsigm(acc2);
        gact[3][tid] = is_g ? ftanh(acc3) : fsigm(acc3);
        __syncthreads();   // gact ready; prev hbuf reads done

        {
            float ig = gact[cb][cj];
            float fg = gact[cb][HH + cj];
            float gg = gact[cb][2 * HH + cj];
            float og = gact[cb][3 * HH + cj];
            c_reg = fg * c_reg + ig * gg;
            float h = og * ftanh(c_reg);
            hbuf[tid] = h;
            g_h1[((size_t)t * BB + (b0 + cb)) * (2 * HH) + dir * HH + cj] = h;
        }
        __syncthreads();   // hbuf ready

        float4 hv = ((const float4*)hbuf)[lane];
        hs0 = hv.x; hs1 = hv.y; hs2 = hv.z; hs3 = hv.w;
        p0 = n0; p1 = n1; p2 = n2; p3 = n3;
    }
}

// ---------------------------------------------------------------------------
// Layer-1 forward input pre-gates. 2048 blocks (b = bid>>1, gate-half =
// bid&1) x 256 thr: gl = tid&127 (gate-local), rg = tid>>7 (row group:
// t 0..255 / 256..511). Both row groups share one 64 KB weight LDS ->
// 2 blocks/CU = 8 waves/CU (fixes r7's 1-wave/SIMD latency exposure).
// ---------------------------------------------------------------------------
__global__ __launch_bounds__(256, 2) void pre_gemm1(
    const float* __restrict__ w_ih,   // [2][G][128] (dir 0 used)
    const float* __restrict__ b_ih,
    const float* __restrict__ b_hh)
{
    const int tid  = threadIdx.x;
    const int gl   = tid & 127;
    const int rg   = tid >> 7;
    const int b    = blockIdx.x >> 1;
    const int gate = (blockIdx.x & 1) * 128 + gl;

    __shared__ __align__(16) float4 w4[32 * 128];   // [kq][gate-local], 64 KB
    const float4* wsrc = (const float4*)w_ih + (size_t)gate * 32;
#pragma unroll
    for (int i = 0; i < 16; ++i) {
        int kq = rg * 16 + i;
        w4[kq * 128 + gl] = wsrc[kq];
    }
    const float bias = b_ih[gate] + b_hh[gate];
    __syncthreads();

    const size_t STRD = (size_t)BB * 128;   // h1 t-stride (floats)
    const size_t OS   = (size_t)BB * GG;    // pre1 t-stride (floats)
    for (int tc = 0; tc < 32; ++tc) {
        const int tbase = rg * 256 + tc * 8;
        const float* hrow = g_h1 + ((size_t)tbase * BB + b) * 128;
        float a0 = bias, a1 = bias, a2 = bias, a3 = bias,
              a4 = bias, a5 = bias, a6 = bias, a7 = bias;
#pragma unroll
        for (int kq = 0; kq < 32; ++kq) {
            float4 wq = w4[kq * 128 + gl];
            const float* hp = hrow + kq * 4;
            float4 q;
            q = *(const float4*)(hp + 0 * STRD); a0 += q.x*wq.x + q.y*wq.y + q.z*wq.z + q.w*wq.w;
            q = *(const float4*)(hp + 1 * STRD); a1 += q.x*wq.x + q.y*wq.y + q.z*wq.z + q.w*wq.w;
            q = *(const float4*)(hp + 2 * STRD); a2 += q.x*wq.x + q.y*wq.y + q.z*wq.z + q.w*wq.w;
            q = *(const float4*)(hp + 3 * STRD); a3 += q.x*wq.x + q.y*wq.y + q.z*wq.z + q.w*wq.w;
            q = *(const float4*)(hp + 4 * STRD); a4 += q.x*wq.x + q.y*wq.y + q.z*wq.z + q.w*wq.w;
            q = *(const float4*)(hp + 5 * STRD); a5 += q.x*wq.x + q.y*wq.y + q.z*wq.z + q.w*wq.w;
            q = *(const float4*)(hp + 6 * STRD); a6 += q.x*wq.x + q.y*wq.y + q.z*wq.z + q.w*wq.w;
            q = *(const float4*)(hp + 7 * STRD); a7 += q.x*wq.x + q.y*wq.y + q.z*wq.z + q.w*wq.w;
        }
        float* op = g_pre1 + ((size_t)tbase * BB + b) * GG + gate;
        op[0] = a0; op[1 * OS] = a1; op[2 * OS] = a2; op[3 * OS] = a3;
        op[4 * OS] = a4; op[5 * OS] = a5; op[6 * OS] = a6; op[7 * OS] = a7;
    }
}

// ---------------------------------------------------------------------------
// Layer 1 forward scan (unchanged from r7): K=64 recurrent matvec + cell.
// 256 blocks x 256 thr, 4 batches/block.
// ---------------------------------------------------------------------------
__global__ __launch_bounds__(256, 2) void lstm_layer1_fwd(
    const float* __restrict__ w_hh)   // [2][G][64] (dir 0 used)
{
    const int tid  = threadIdx.x;
    const int b0   = blockIdx.x * 4;
    const int lane = tid & 63;

    __shared__ __align__(16) float4 wlds[12 * 256];   // 48 KB
    __shared__ float gact[4][GG];
    __shared__ __align__(16) float hbuf[256];

    const float4* wsrc = (const float4*)w_hh + (size_t)tid * 16;
#pragma unroll
    for (int j4 = 0; j4 < 12; ++j4) wlds[j4 * 256 + tid] = wsrc[j4];
    float4 wr0 = wsrc[12], wr1 = wsrc[13], wr2 = wsrc[14], wr3 = wsrc[15];
    __syncthreads();

    float c_reg = 0.f;
    float hs0 = 0.f, hs1 = 0.f, hs2 = 0.f, hs3 = 0.f;
    const int cb = tid >> 6, cj = tid & 63;
    const bool is_g = (cb == 2);

    float p0 = g_pre1[((size_t)0 * BB + (b0 + 0)) * GG + tid];
    float p1 = g_pre1[((size_t)0 * BB + (b0 + 1)) * GG + tid];
    float p2 = g_pre1[((size_t)0 * BB + (b0 + 2)) * GG + tid];
    float p3 = g_pre1[((size_t)0 * BB + (b0 + 3)) * GG + tid];

    for (int t = 0; t < TT; ++t) {
        float n0 = 0.f, n1 = 0.f, n2 = 0.f, n3 = 0.f;
        if (t + 1 < TT) {
            n0 = g_pre1[((size_t)(t + 1) * BB + (b0 + 0)) * GG + tid];
            n1 = g_pre1[((size_t)(t + 1) * BB + (b0 + 1)) * GG + tid];
            n2 = g_pre1[((size_t)(t + 1) * BB + (b0 + 2)) * GG + tid];
            n3 = g_pre1[((size_t)(t + 1) * BB + (b0 + 3)) * GG + tid];
        }
        float acc0 = p0, acc1 = p1, acc2 = p2, acc3 = p3;
#pragma unroll
        for (int j4 = 0; j4 < 12; ++j4) {
            float4 wq = wlds[j4 * 256 + tid];
            HM(j4, wq);
        }
        HM(12, wr0); HM(13, wr1); HM(14, wr2); HM(15, wr3);

        gact[0][tid] = is_g ? ftanh(acc0) : fsigm(acc0);
        gact[1][tid] = is_g ? ftanh(acc1) : fsigm(acc1);
        gact[2][tid] = is_g ? ftanh(acc2) : fsigm(acc2);
        gact[3][tid] = is_g ? ftanh(acc3) : fsigm(acc3);
        __syncthreads();

        {
            float ig = gact[cb][cj];
            float fg = gact[cb][HH + cj];
            float gg = gact[cb][2 * HH + cj];
            float og = gact[cb][3 * HH + cj];
            c_reg = fg * c_reg + ig * gg;
            float h = og * ftanh(c_reg);
            hbuf[tid] = h;
            if (t == TT - 1) g_hf[(size_t)(b0 + cb) * HH + cj] = h;
        }
        __syncthreads();

        float4 hv = ((const float4*)hbuf)[lane];
        hs0 = hv.x; hs1 = hv.y; hs2 = hv.z; hs3 = hv.w;
        p0 = n0; p1 = n1; p2 = n2; p3 = n3;
    }
}

// ---------------------------------------------------------------------------
// Layer 1 backward single step (zero state on h1[T-1]) + FC head.
// Unchanged from r7 (runs once; cost negligible).
// ---------------------------------------------------------------------------
#define FMAC4(W, P0, P1, P2, P3, K) do{                                   \
    float4 v_;                                                           \
    v_ = (P0)[K]; acc0 += W.x*v_.x; acc0 += W.y*v_.y; acc0 += W.z*v_.z; acc0 += W.w*v_.w; \
    v_ = (P1)[K]; acc1 += W.x*v_.x; acc1 += W.y*v_.y; acc1 += W.z*v_.z; acc1 += W.w*v_.w; \
    v_ = (P2)[K]; acc2 += W.x*v_.x; acc2 += W.y*v_.y; acc2 += W.z*v_.z; acc2 += W.w*v_.w; \
    v_ = (P3)[K]; acc3 += W.x*v_.x; acc3 += W.y*v_.y; acc3 += W.z*v_.z; acc3 += W.w*v_.w; \
}while(0)

__global__ __launch_bounds__(256, 2) void lstm_final(
    const float* __restrict__ w_ih,   // [2][G][128] (dir 1)
    const float* __restrict__ b_ih,
    const float* __restrict__ b_hh,
    const float* __restrict__ fc_w,   // [2][128]
    const float* __restrict__ fc_b,   // [2]
    float* __restrict__ out)          // [B][2]
{
    const int tid = threadIdx.x;
    const int b0  = blockIdx.x * 4;

    __shared__ __align__(16) float x_lds[4][128];
    __shared__ __align__(16) float gact[4][GG];
    __shared__ __align__(16) float last[4][128];

#pragma unroll
    for (int r = 0; r < 2; ++r) {
        int idx = tid + r * 256;
        int b = idx >> 7, col = idx & 127;
        x_lds[b][col] = g_h1[((size_t)(TT - 1) * BB + (b0 + b)) * 128 + col];
    }

    const float4* p = (const float4*)(w_ih + ((size_t)GG + tid) * 128);
    float4 w0 = p[0],  w1 = p[1],  w2 = p[2],  w3 = p[3],  w4 = p[4],  w5 = p[5],
           w6 = p[6],  w7 = p[7],  w8 = p[8],  w9 = p[9],  w10 = p[10], w11 = p[11],
           w12 = p[12], w13 = p[13], w14 = p[14], w15 = p[15], w16 = p[16], w17 = p[17],
           w18 = p[18], w19 = p[19], w20 = p[20], w21 = p[21], w22 = p[22], w23 = p[23],
           w24 = p[24], w25 = p[25], w26 = p[26], w27 = p[27], w28 = p[28], w29 = p[29],
           w30 = p[30], w31 = p[31];
    const float bias = b_ih[GG + tid] + b_hh[GG + tid];
    __syncthreads();

    const float4* xb0 = (const float4*)x_lds[0];
    const float4* xb1 = (const float4*)x_lds[1];
    const float4* xb2 = (const float4*)x_lds[2];
    const float4* xb3 = (const float4*)x_lds[3];

    float acc0 = bias, acc1 = bias, acc2 = bias, acc3 = bias;
    FMAC4(w0, xb0, xb1, xb2, xb3, 0);   FMAC4(w1, xb0, xb1, xb2, xb3, 1);
    FMAC4(w2, xb0, xb1, xb2, xb3, 2);   FMAC4(w3, xb0, xb1, xb2, xb3, 3);
    FMAC4(w4, xb0, xb1, xb2, xb3, 4);   FMAC4(w5, xb0, xb1, xb2, xb3, 5);
    FMAC4(w6, xb0, xb1, xb2, xb3, 6);   FMAC4(w7, xb0, xb1, xb2, xb3, 7);
    FMAC4(w8, xb0, xb1, xb2, xb3, 8);   FMAC4(w9, xb0, xb1, xb2, xb3, 9);
    FMAC4(w10, xb0, xb1, xb2, xb3, 10); FMAC4(w11, xb0, xb1, xb2, xb3, 11);
    FMAC4(w12, xb0, xb1, xb2, xb3, 12); FMAC4(w13, xb0, xb1, xb2, xb3, 13);
    FMAC4(w14, xb0, xb1, xb2, xb3, 14); FMAC4(w15, xb0, xb1, xb2, xb3, 15);
    FMAC4(w16, xb0, xb1, xb2, xb3, 16); FMAC4(w17, xb0, xb1, xb2, xb3, 17);
    FMAC4(w18, xb0, xb1, xb2, xb3, 18); FMAC4(w19, xb0, xb1, xb2, xb3, 19);
    FMAC4(w20, xb0, xb1, xb2, xb3, 20); FMAC4(w21, xb0, xb1, xb2, xb3, 21);
    FMAC4(w22, xb0, xb1, xb2, xb3, 22); FMAC4(w23, xb0, xb1, xb2, xb3, 23);
    FMAC4(w24, xb0, xb1, xb2, xb3, 24); FMAC4(w25, xb0, xb1, xb2, xb3, 25);
    FMAC4(w26, xb0, xb1, xb2, xb3, 26); FMAC4(w27, xb0, xb1, xb2, xb3, 27);
    FMAC4(w28, xb0, xb1, xb2, xb3, 28); FMAC4(w29, xb0, xb1, xb2, xb3, 29);
    FMAC4(w30, xb0, xb1, xb2, xb3, 30); FMAC4(w31, xb0, xb1, xb2, xb3, 31);

    const bool is_g = ((tid >> 6) == 2);
    gact[0][tid] = is_g ? ftanh(acc0) : fsigm(acc0);
    gact[1][tid] = is_g ? ftanh(acc1) : fsigm(acc1);
    gact[2][tid] = is_g ? ftanh(acc2) : fsigm(acc2);
    gact[3][tid] = is_g ? ftanh(acc3) : fsigm(acc3);
    __syncthreads();

    {
        const int cb = tid >> 6, cj = tid & 63;
        float ig = gact[cb][cj];
        float gg = gact[cb][2 * HH + cj];
        float og = gact[cb][3 * HH + cj];
        float c = ig * gg;
        float h = og * ftanh(c);
        last[cb][HH + cj] = h;
        last[cb][cj] = g_hf[(size_t)(b0 + cb) * HH + cj];
    }
    __syncthreads();

    if (tid < 8) {
        int b = tid >> 1, o = tid & 1;
        float a = fc_b[o];
#pragma unroll
        for (int j = 0; j < 128; ++j) a += fc_w[o * 128 + j] * last[b][j];
        out[(size_t)(b0 + b) * 2 + o] = a;
    }
}

extern "C" void kernel_launch(void* const* d_in, const int* in_sizes, int n_in,
                              void* d_out, int out_size, void* d_ws, size_t ws_size,
                              hipStream_t stream) {
    const float* x     = (const float*)d_in[0];
    const float* w_ih0 = (const float*)d_in[1];
    const float* w_hh0 = (const float*)d_in[2];
    const float* b_ih0 = (const float*)d_in[3];
    const float* b_hh0 = (const float*)d_in[4];
    const float* w_ih1 = (const float*)d_in[5];
    const float* w_hh1 = (const float*)d_in[6];
    const float* b_ih1 = (const float*)d_in[7];
    const float* b_hh1 = (const float*)d_in[8];
    const float* fc_w  = (const float*)d_in[9];
    const float* fc_b  = (const float*)d_in[10];
    float* out = (float*)d_out;

    pre_gemm0<<<2048, 256, 0, stream>>>(x, w_ih0, b_ih0, b_hh0);
    lstm_layer0_scan<<<512, 256, 0, stream>>>(w_hh0);
    pre_gemm1<<<2048, 256, 0, stream>>>(w_ih1, b_ih1, b_hh1);
    lstm_layer1_fwd<<<256, 256, 0, stream>>>(w_hh1);
    lstm_final<<<256, 256, 0, stream>>>(w_ih1, b_ih1, b_hh1, fc_w, fc_b, out);
}

// Round 9
// 4701.273 us; speedup vs baseline: 5.4056x; 1.5089x over previous
//
#include <hip/hip_runtime.h>

#define TT 512
#define BB 1024
#define FF 32
#define HH 64
#define GG 256   // 4*H gates per direction

// Static device scratch (ws_size-independent). Fully overwritten every call.
__device__ float g_h1[(size_t)TT * BB * 2 * HH];   // [T][B][128] layer-1 input, 256 MB
__device__ float g_pre0[(size_t)2 * TT * BB * GG]; // [dir][T][B][256] layer-0 pre-gates, 1.07 GB
__device__ float g_pre1[(size_t)TT * BB * GG];     // [T][B][256] layer-1 fwd pre-gates, 537 MB
__device__ float g_hf[(size_t)BB * HH];            // [B][64] final fwd h of layer1

__device__ __forceinline__ float fsigm(float x) {
    float e = __builtin_amdgcn_exp2f(x * -1.44269504088896f);
    return __builtin_amdgcn_rcpf(1.0f + e);
}
__device__ __forceinline__ float ftanh(float x) {
    float e = __builtin_amdgcn_exp2f(x * -2.88539008177793f);
    return 2.0f * __builtin_amdgcn_rcpf(1.0f + e) - 1.0f;
}
// Wave-uniform broadcast via v_readlane (VALU->SGPR, zero LDS-pipe cost).
__device__ __forceinline__ float rlane(float v, int l) {
    return __int_as_float(__builtin_amdgcn_readlane(__float_as_int(v), l));
}

// h-matvec step: acc_b += sum_c h[b][4*J4+c] * w[gate][4*J4+c].
// h_flat[b*64+j] staged as lane (b*16+j4) component c of hs0..hs3.
#define HM(J4, WQ) do{                                                        \
    acc0 += rlane(hs0,(J4)   )*(WQ).x + rlane(hs1,(J4)   )*(WQ).y             \
          + rlane(hs2,(J4)   )*(WQ).z + rlane(hs3,(J4)   )*(WQ).w;            \
    acc1 += rlane(hs0,16+(J4))*(WQ).x + rlane(hs1,16+(J4))*(WQ).y             \
          + rlane(hs2,16+(J4))*(WQ).z + rlane(hs3,16+(J4))*(WQ).w;            \
    acc2 += rlane(hs0,32+(J4))*(WQ).x + rlane(hs1,32+(J4))*(WQ).y             \
          + rlane(hs2,32+(J4))*(WQ).z + rlane(hs3,32+(J4))*(WQ).w;            \
    acc3 += rlane(hs0,48+(J4))*(WQ).x + rlane(hs1,48+(J4))*(WQ).y             \
          + rlane(hs2,48+(J4))*(WQ).z + rlane(hs3,48+(J4))*(WQ).w;            \
}while(0)

// ---------------------------------------------------------------------------
// Layer-0 input pre-gates. 2048 blocks (b = bid>>1, dir = bid&1) x 256 thr
// (thread = gate). Weights in 32 KB LDS; x tiles (8 t-rows) staged into a
// double-buffered 2 KB LDS buffer via COALESCED loads (1 float/thread) —
// fixes r8's wave-uniform-load latency stall.
// ---------------------------------------------------------------------------
__global__ __launch_bounds__(256, 4) void pre_gemm0(
    const float* __restrict__ x,      // [B][T][F]
    const float* __restrict__ w_ih,   // [2][G][F]
    const float* __restrict__ b_ih,
    const float* __restrict__ b_hh)
{
    const int tid = threadIdx.x;          // gate
    const int b   = blockIdx.x >> 1;
    const int dir = blockIdx.x & 1;

    __shared__ __align__(16) float4 w4[8 * 256];    // [kq][gate], 32 KB
    __shared__ __align__(16) float xbuf[2][256];    // 8 t-rows x 32 f, dbuf

    const float4* wsrc = (const float4*)(w_ih + ((size_t)dir * GG + tid) * FF);
#pragma unroll
    for (int kq = 0; kq < 8; ++kq) w4[kq * 256 + tid] = wsrc[kq];
    const float bias = b_ih[dir * GG + tid] + b_hh[dir * GG + tid];

    const float* xbase = x + (size_t)b * TT * FF;
    xbuf[0][tid] = xbase[tid];            // tile 0 (rows 0..7), coalesced
    const size_t OS = (size_t)BB * GG;

    for (int tc = 0; tc < 64; ++tc) {
        const int cur = tc & 1;
        __syncthreads();   // xbuf[cur] ready; prev reads of xbuf[1-cur] done

        float vnext = 0.f;
        if (tc + 1 < 64) vnext = xbase[(tc + 1) * 256 + tid];   // coalesced

        float a0 = bias, a1 = bias, a2 = bias, a3 = bias,
              a4 = bias, a5 = bias, a6 = bias, a7 = bias;
#pragma unroll
        for (int kq = 0; kq < 8; ++kq) {
            float4 wq = w4[kq * 256 + tid];
            const float4* xr = (const float4*)xbuf[cur];
            float4 q;
            q = xr[0 * 8 + kq]; a0 += q.x*wq.x + q.y*wq.y + q.z*wq.z + q.w*wq.w;
            q = xr[1 * 8 + kq]; a1 += q.x*wq.x + q.y*wq.y + q.z*wq.z + q.w*wq.w;
            q = xr[2 * 8 + kq]; a2 += q.x*wq.x + q.y*wq.y + q.z*wq.z + q.w*wq.w;
            q = xr[3 * 8 + kq]; a3 += q.x*wq.x + q.y*wq.y + q.z*wq.z + q.w*wq.w;
            q = xr[4 * 8 + kq]; a4 += q.x*wq.x + q.y*wq.y + q.z*wq.z + q.w*wq.w;
            q = xr[5 * 8 + kq]; a5 += q.x*wq.x + q.y*wq.y + q.z*wq.z + q.w*wq.w;
            q = xr[6 * 8 + kq]; a6 += q.x*wq.x + q.y*wq.y + q.z*wq.z + q.w*wq.w;
            q = xr[7 * 8 + kq]; a7 += q.x*wq.x + q.y*wq.y + q.z*wq.z + q.w*wq.w;
        }
        float* op = g_pre0 + (((size_t)dir * TT + tc * 8) * BB + b) * GG + tid;
        op[0] = a0; op[1 * OS] = a1; op[2 * OS] = a2; op[3 * OS] = a3;
        op[4 * OS] = a4; op[5 * OS] = a5; op[6 * OS] = a6; op[7 * OS] = a7;

        if (tc + 1 < 64) xbuf[1 - cur][tid] = vnext;
    }
}

// ---------------------------------------------------------------------------
// Layer 0 recurrent-only scan (unchanged from r8).
// ---------------------------------------------------------------------------
__global__ __launch_bounds__(256, 2) void lstm_layer0_scan(
    const float* __restrict__ w_hh)   // [2][G][64]
{
    const int tid  = threadIdx.x;
    const int dir  = blockIdx.x & 1;
    const int b0   = (blockIdx.x >> 1) * 4;
    const int lane = tid & 63;

    __shared__ __align__(16) float4 wlds[12 * 256];   // 48 KB
    __shared__ float gact[4][GG];
    __shared__ __align__(16) float hbuf[256];

    const float4* wsrc = (const float4*)(w_hh + (size_t)dir * GG * HH) + (size_t)tid * 16;
#pragma unroll
    for (int j4 = 0; j4 < 12; ++j4) wlds[j4 * 256 + tid] = wsrc[j4];
    float4 wr0 = wsrc[12], wr1 = wsrc[13], wr2 = wsrc[14], wr3 = wsrc[15];
    __syncthreads();

    float c_reg = 0.f;
    float hs0 = 0.f, hs1 = 0.f, hs2 = 0.f, hs3 = 0.f;
    const int cb = tid >> 6, cj = tid & 63;
    const bool is_g = (cb == 2);

    const size_t DOFF = (size_t)dir * TT;
    int t0 = dir ? (TT - 1) : 0;
    float p0 = g_pre0[((DOFF + t0) * BB + (b0 + 0)) * GG + tid];
    float p1 = g_pre0[((DOFF + t0) * BB + (b0 + 1)) * GG + tid];
    float p2 = g_pre0[((DOFF + t0) * BB + (b0 + 2)) * GG + tid];
    float p3 = g_pre0[((DOFF + t0) * BB + (b0 + 3)) * GG + tid];

    for (int s = 0; s < TT; ++s) {
        const int t = dir ? (TT - 1 - s) : s;
        float n0 = 0.f, n1 = 0.f, n2 = 0.f, n3 = 0.f;
        if (s + 1 < TT) {
            int tn = dir ? (TT - 2 - s) : (s + 1);
            n0 = g_pre0[((DOFF + tn) * BB + (b0 + 0)) * GG + tid];
            n1 = g_pre0[((DOFF + tn) * BB + (b0 + 1)) * GG + tid];
            n2 = g_pre0[((DOFF + tn) * BB + (b0 + 2)) * GG + tid];
            n3 = g_pre0[((DOFF + tn) * BB + (b0 + 3)) * GG + tid];
        }
        float acc0 = p0, acc1 = p1, acc2 = p2, acc3 = p3;
#pragma unroll
        for (int j4 = 0; j4 < 12; ++j4) {
            float4 wq = wlds[j4 * 256 + tid];
            HM(j4, wq);
        }
        HM(12, wr0); HM(13, wr1); HM(14, wr2); HM(15, wr3);

        gact[0][tid] = is_g ? ftanh(acc0) : fsigm(acc0);
        gact[1][tid] = is_g ? ftanh(acc1) : fsigm(acc1);
        gact[2][tid] = is_g ? ftanh(acc2) : fsigm(acc2);
        gact[3][tid] = is_g ? ftanh(acc3) : fsigm(acc3);
        __syncthreads();   // gact ready; prev hbuf reads done

        {
            float ig = gact[cb][cj];
            float fg = gact[cb][HH + cj];
            float gg = gact[cb][2 * HH + cj];
            float og = gact[cb][3 * HH + cj];
            c_reg = fg * c_reg + ig * gg;
            float h = og * ftanh(c_reg);
            hbuf[tid] = h;
            g_h1[((size_t)t * BB + (b0 + cb)) * (2 * HH) + dir * HH + cj] = h;
        }
        __syncthreads();   // hbuf ready

        float4 hv = ((const float4*)hbuf)[lane];
        hs0 = hv.x; hs1 = hv.y; hs2 = hv.z; hs3 = hv.w;
        p0 = n0; p1 = n1; p2 = n2; p3 = n3;
    }
}

// ---------------------------------------------------------------------------
// Layer-1 forward input pre-gates. 2048 blocks (b = bid>>1, gate-half =
// bid&1) x 256 thr: gl = tid&127, rg = tid>>7 (rows 0..3 / 4..7 of each
// 8-row tile; full K-sums, no partial reduction). Weight quads 0..27 in
// 56 KB LDS + quads 28..31 in regs; h1 tiles staged via COALESCED loads
// into an 8 KB double buffer (fixes the r8 uniform-load stall). 64 KB total.
// ---------------------------------------------------------------------------
__global__ __launch_bounds__(256, 2) void pre_gemm1(
    const float* __restrict__ w_ih,   // [2][G][128] (dir 0 used)
    const float* __restrict__ b_ih,
    const float* __restrict__ b_hh)
{
    const int tid  = threadIdx.x;
    const int gl   = tid & 127;
    const int rg   = tid >> 7;
    const int b    = blockIdx.x >> 1;
    const int gate = (blockIdx.x & 1) * 128 + gl;

    __shared__ __align__(16) float4 w4[28 * 128];       // quads 0..27, 56 KB
    __shared__ __align__(16) float4 hstg[2][8 * 32];    // 8 t-rows x 32 q, dbuf 8 KB

    const float4* wsrc = (const float4*)w_ih + (size_t)gate * 32;
#pragma unroll
    for (int i = 0; i < 14; ++i) {
        int kq = rg * 14 + i;
        w4[kq * 128 + gl] = wsrc[kq];
    }
    float4 wr0 = wsrc[28], wr1 = wsrc[29], wr2 = wsrc[30], wr3 = wsrc[31];
    const float bias = b_ih[gate] + b_hh[gate];

    // stage tile 0: thread -> (row = tid>>5, quad = tid&31), coalesced 16B
    const int srow = tid >> 5, sq = tid & 31;
    hstg[0][srow * 32 + sq] =
        *((const float4*)(g_h1 + ((size_t)srow * BB + b) * 128) + sq);

    const size_t RS = (size_t)BB * GG;    // pre1 t-stride (floats)

    for (int tc = 0; tc < 64; ++tc) {
        const int cur = tc & 1;
        __syncthreads();   // hstg[cur] + w4 ready; prev reads of other buf done

        float4 vnext = make_float4(0.f, 0.f, 0.f, 0.f);
        if (tc + 1 < 64)
            vnext = *((const float4*)(g_h1 +
                      ((size_t)((tc + 1) * 8 + srow) * BB + b) * 128) + sq);

        const float4* hr0 = &hstg[cur][(rg * 4 + 0) * 32];
        const float4* hr1 = &hstg[cur][(rg * 4 + 1) * 32];
        const float4* hr2 = &hstg[cur][(rg * 4 + 2) * 32];
        const float4* hr3 = &hstg[cur][(rg * 4 + 3) * 32];

        float a0 = bias, a1 = bias, a2 = bias, a3 = bias;
#pragma unroll
        for (int kq = 0; kq < 28; ++kq) {
            float4 wq = w4[kq * 128 + gl];
            float4 q;
            q = hr0[kq]; a0 += q.x*wq.x + q.y*wq.y + q.z*wq.z + q.w*wq.w;
            q = hr1[kq]; a1 += q.x*wq.x + q.y*wq.y + q.z*wq.z + q.w*wq.w;
            q = hr2[kq]; a2 += q.x*wq.x + q.y*wq.y + q.z*wq.z + q.w*wq.w;
            q = hr3[kq]; a3 += q.x*wq.x + q.y*wq.y + q.z*wq.z + q.w*wq.w;
        }
        {
            float4 q;
            q = hr0[28]; a0 += q.x*wr0.x + q.y*wr0.y + q.z*wr0.z + q.w*wr0.w;
            q = hr1[28]; a1 += q.x*wr0.x + q.y*wr0.y + q.z*wr0.z + q.w*wr0.w;
            q = hr2[28]; a2 += q.x*wr0.x + q.y*wr0.y + q.z*wr0.z + q.w*wr0.w;
            q = hr3[28]; a3 += q.x*wr0.x + q.y*wr0.y + q.z*wr0.z + q.w*wr0.w;
            q = hr0[29]; a0 += q.x*wr1.x + q.y*wr1.y + q.z*wr1.z + q.w*wr1.w;
            q = hr1[29]; a1 += q.x*wr1.x + q.y*wr1.y + q.z*wr1.z + q.w*wr1.w;
            q = hr2[29]; a2 += q.x*wr1.x + q.y*wr1.y + q.z*wr1.z + q.w*wr1.w;
            q = hr3[29]; a3 += q.x*wr1.x + q.y*wr1.y + q.z*wr1.z + q.w*wr1.w;
            q = hr0[30]; a0 += q.x*wr2.x + q.y*wr2.y + q.z*wr2.z + q.w*wr2.w;
            q = hr1[30]; a1 += q.x*wr2.x + q.y*wr2.y + q.z*wr2.z + q.w*wr2.w;
            q = hr2[30]; a2 += q.x*wr2.x + q.y*wr2.y + q.z*wr2.z + q.w*wr2.w;
            q = hr3[30]; a3 += q.x*wr2.x + q.y*wr2.y + q.z*wr2.z + q.w*wr2.w;
            q = hr0[31]; a0 += q.x*wr3.x + q.y*wr3.y + q.z*wr3.z + q.w*wr3.w;
            q = hr1[31]; a1 += q.x*wr3.x + q.y*wr3.y + q.z*wr3.z + q.w*wr3.w;
            q = hr2[31]; a2 += q.x*wr3.x + q.y*wr3.y + q.z*wr3.z + q.w*wr3.w;
            q = hr3[31]; a3 += q.x*wr3.x + q.y*wr3.y + q.z*wr3.z + q.w*wr3.w;
        }
        {
            const int tb = tc * 8 + rg * 4;
            float* op = g_pre1 + ((size_t)tb * BB + b) * GG + gate;
            op[0 * RS] = a0; op[1 * RS] = a1; op[2 * RS] = a2; op[3 * RS] = a3;
        }
        if (tc + 1 < 64) hstg[1 - cur][srow * 32 + sq] = vnext;
    }
}

// ---------------------------------------------------------------------------
// Layer 1 forward scan (unchanged from r8).
// ---------------------------------------------------------------------------
__global__ __launch_bounds__(256, 2) void lstm_layer1_fwd(
    const float* __restrict__ w_hh)   // [2][G][64] (dir 0 used)
{
    const int tid  = threadIdx.x;
    const int b0   = blockIdx.x * 4;
    const int lane = tid & 63;

    __shared__ __align__(16) float4 wlds[12 * 256];   // 48 KB
    __shared__ float gact[4][GG];
    __shared__ __align__(16) float hbuf[256];

    const float4* wsrc = (const float4*)w_hh + (size_t)tid * 16;
#pragma unroll
    for (int j4 = 0; j4 < 12; ++j4) wlds[j4 * 256 + tid] = wsrc[j4];
    float4 wr0 = wsrc[12], wr1 = wsrc[13], wr2 = wsrc[14], wr3 = wsrc[15];
    __syncthreads();

    float c_reg = 0.f;
    float hs0 = 0.f, hs1 = 0.f, hs2 = 0.f, hs3 = 0.f;
    const int cb = tid >> 6, cj = tid & 63;
    const bool is_g = (cb == 2);

    float p0 = g_pre1[((size_t)0 * BB + (b0 + 0)) * GG + tid];
    float p1 = g_pre1[((size_t)0 * BB + (b0 + 1)) * GG + tid];
    float p2 = g_pre1[((size_t)0 * BB + (b0 + 2)) * GG + tid];
    float p3 = g_pre1[((size_t)0 * BB + (b0 + 3)) * GG + tid];

    for (int t = 0; t < TT; ++t) {
        float n0 = 0.f, n1 = 0.f, n2 = 0.f, n3 = 0.f;
        if (t + 1 < TT) {
            n0 = g_pre1[((size_t)(t + 1) * BB + (b0 + 0)) * GG + tid];
            n1 = g_pre1[((size_t)(t + 1) * BB + (b0 + 1)) * GG + tid];
            n2 = g_pre1[((size_t)(t + 1) * BB + (b0 + 2)) * GG + tid];
            n3 = g_pre1[((size_t)(t + 1) * BB + (b0 + 3)) * GG + tid];
        }
        float acc0 = p0, acc1 = p1, acc2 = p2, acc3 = p3;
#pragma unroll
        for (int j4 = 0; j4 < 12; ++j4) {
            float4 wq = wlds[j4 * 256 + tid];
            HM(j4, wq);
        }
        HM(12, wr0); HM(13, wr1); HM(14, wr2); HM(15, wr3);

        gact[0][tid] = is_g ? ftanh(acc0) : fsigm(acc0);
        gact[1][tid] = is_g ? ftanh(acc1) : fsigm(acc1);
        gact[2][tid] = is_g ? ftanh(acc2) : fsigm(acc2);
        gact[3][tid] = is_g ? ftanh(acc3) : fsigm(acc3);
        __syncthreads();

        {
            float ig = gact[cb][cj];
            float fg = gact[cb][HH + cj];
            float gg = gact[cb][2 * HH + cj];
            float og = gact[cb][3 * HH + cj];
            c_reg = fg * c_reg + ig * gg;
            float h = og * ftanh(c_reg);
            hbuf[tid] = h;
            if (t == TT - 1) g_hf[(size_t)(b0 + cb) * HH + cj] = h;
        }
        __syncthreads();

        float4 hv = ((const float4*)hbuf)[lane];
        hs0 = hv.x; hs1 = hv.y; hs2 = hv.z; hs3 = hv.w;
        p0 = n0; p1 = n1; p2 = n2; p3 = n3;
    }
}

// ---------------------------------------------------------------------------
// Layer 1 backward single step (zero state on h1[T-1]) + FC head.
// Unchanged from r8 (runs once; cost negligible).
// ---------------------------------------------------------------------------
#define FMAC4(W, P0, P1, P2, P3, K) do{                                   \
    float4 v_;                                                           \
    v_ = (P0)[K]; acc0 += W.x*v_.x; acc0 += W.y*v_.y; acc0 += W.z*v_.z; acc0 += W.w*v_.w; \
    v_ = (P1)[K]; acc1 += W.x*v_.x; acc1 += W.y*v_.y; acc1 += W.z*v_.z; acc1 += W.w*v_.w; \
    v_ = (P2)[K]; acc2 += W.x*v_.x; acc2 += W.y*v_.y; acc2 += W.z*v_.z; acc2 += W.w*v_.w; \
    v_ = (P3)[K]; acc3 += W.x*v_.x; acc3 += W.y*v_.y; acc3 += W.z*v_.z; acc3 += W.w*v_.w; \
}while(0)

__global__ __launch_bounds__(256, 2) void lstm_final(
    const float* __restrict__ w_ih,   // [2][G][128] (dir 1)
    const float* __restrict__ b_ih,
    const float* __restrict__ b_hh,
    const float* __restrict__ fc_w,   // [2][128]
    const float* __restrict__ fc_b,   // [2]
    float* __restrict__ out)          // [B][2]
{
    const int tid = threadIdx.x;
    const int b0  = blockIdx.x * 4;

    __shared__ __align__(16) float x_lds[4][128];
    __shared__ __align__(16) float gact[4][GG];
    __shared__ __align__(16) float last[4][128];

#pragma unroll
    for (int r = 0; r < 2; ++r) {
        int idx = tid + r * 256;
        int b = idx >> 7, col = idx & 127;
        x_lds[b][col] = g_h1[((size_t)(TT - 1) * BB + (b0 + b)) * 128 + col];
    }

    const float4* p = (const float4*)(w_ih + ((size_t)GG + tid) * 128);
    float4 w0 = p[0],  w1 = p[1],  w2 = p[2],  w3 = p[3],  w4 = p[4],  w5 = p[5],
           w6 = p[6],  w7 = p[7],  w8 = p[8],  w9 = p[9],  w10 = p[10], w11 = p[11],
           w12 = p[12], w13 = p[13], w14 = p[14], w15 = p[15], w16 = p[16], w17 = p[17],
           w18 = p[18], w19 = p[19], w20 = p[20], w21 = p[21], w22 = p[22], w23 = p[23],
           w24 = p[24], w25 = p[25], w26 = p[26], w27 = p[27], w28 = p[28], w29 = p[29],
           w30 = p[30], w31 = p[31];
    const float bias = b_ih[GG + tid] + b_hh[GG + tid];
    __syncthreads();

    const float4* xb0 = (const float4*)x_lds[0];
    const float4* xb1 = (const float4*)x_lds[1];
    const float4* xb2 = (const float4*)x_lds[2];
    const float4* xb3 = (const float4*)x_lds[3];

    float acc0 = bias, acc1 = bias, acc2 = bias, acc3 = bias;
    FMAC4(w0, xb0, xb1, xb2, xb3, 0);   FMAC4(w1, xb0, xb1, xb2, xb3, 1);
    FMAC4(w2, xb0, xb1, xb2, xb3, 2);   FMAC4(w3, xb0, xb1, xb2, xb3, 3);
    FMAC4(w4, xb0, xb1, xb2, xb3, 4);   FMAC4(w5, xb0, xb1, xb2, xb3, 5);
    FMAC4(w6, xb0, xb1, xb2, xb3, 6);   FMAC4(w7, xb0, xb1, xb2, xb3, 7);
    FMAC4(w8, xb0, xb1, xb2, xb3, 8);   FMAC4(w9, xb0, xb1, xb2, xb3, 9);
    FMAC4(w10, xb0, xb1, xb2, xb3, 10); FMAC4(w11, xb0, xb1, xb2, xb3, 11);
    FMAC4(w12, xb0, xb1, xb2, xb3, 12); FMAC4(w13, xb0, xb1, xb2, xb3, 13);
    FMAC4(w14, xb0, xb1, xb2, xb3, 14); FMAC4(w15, xb0, xb1, xb2, xb3, 15);
    FMAC4(w16, xb0, xb1, xb2, xb3, 16); FMAC4(w17, xb0, xb1, xb2, xb3, 17);
    FMAC4(w18, xb0, xb1, xb2, xb3, 18); FMAC4(w19, xb0, xb1, xb2, xb3, 19);
    FMAC4(w20, xb0, xb1, xb2, xb3, 20); FMAC4(w21, xb0, xb1, xb2, xb3, 21);
    FMAC4(w22, xb0, xb1, xb2, xb3, 22); FMAC4(w23, xb0, xb1, xb2, xb3, 23);
    FMAC4(w24, xb0, xb1, xb2, xb3, 24); FMAC4(w25, xb0, xb1, xb2, xb3, 25);
    FMAC4(w26, xb0, xb1, xb2, xb3, 26); FMAC4(w27, xb0, xb1, xb2, xb3, 27);
    FMAC4(w28, xb0, xb1, xb2, xb3, 28); FMAC4(w29, xb0, xb1, xb2, xb3, 29);
    FMAC4(w30, xb0, xb1, xb2, xb3, 30); FMAC4(w31, xb0, xb1, xb2, xb3, 31);

    const bool is_g = ((tid >> 6) == 2);
    gact[0][tid] = is_g ? ftanh(acc0) : fsigm(acc0);
    gact[1][tid] = is_g ? ftanh(acc1) : fsigm(acc1);
    gact[2][tid] = is_g ? ftanh(acc2) : fsigm(acc2);
    gact[3][tid] = is_g ? ftanh(acc3) : fsigm(acc3);
    __syncthreads();

    {
        const int cb = tid >> 6, cj = tid & 63;
        float ig = gact[cb][cj];
        float gg = gact[cb][2 * HH + cj];
        float og = gact[cb][3 * HH + cj];
        float c = ig * gg;
        float h = og * ftanh(c);
        last[cb][HH + cj] = h;
        last[cb][cj] = g_hf[(size_t)(b0 + cb) * HH + cj];
    }
    __syncthreads();

    if (tid < 8) {
        int b = tid >> 1, o = tid & 1;
        float a = fc_b[o];
#pragma unroll
        for (int j = 0; j < 128; ++j) a += fc_w[o * 128 + j] * last[b][j];
        out[(size_t)(b0 + b) * 2 + o] = a;
    }
}

extern "C" void kernel_launch(void* const* d_in, const int* in_sizes, int n_in,
                              void* d_out, int out_size, void* d_ws, size_t ws_size,
                              hipStream_t stream) {
    const float* x     = (const float*)d_in[0];
    const float* w_ih0 = (const float*)d_in[1];
    const float* w_hh0 = (const float*)d_in[2];
    const float* b_ih0 = (const float*)d_in[3];
    const float* b_hh0 = (const float*)d_in[4];
    const float* w_ih1 = (const float*)d_in[5];
    const float* w_hh1 = (const float*)d_in[6];
    const float* b_ih1 = (const float*)d_in[7];
    const float* b_hh1 = (const float*)d_in[8];
    const float* fc_w  = (const float*)d_in[9];
    const float* fc_b  = (const float*)d_in[10];
    float* out = (float*)d_out;

    pre_gemm0<<<2048, 256, 0, stream>>>(x, w_ih0, b_ih0, b_hh0);
    lstm_layer0_scan<<<512, 256, 0, stream>>>(w_hh0);
    pre_gemm1<<<2048, 256, 0, stream>>>(w_ih1, b_ih1, b_hh1);
    lstm_layer1_fwd<<<256, 256, 0, stream>>>(w_hh1);
    lstm_final<<<256, 256, 0, stream>>>(w_ih1, b_ih1, b_hh1, fc_w, fc_b, out);
}

// Round 10
// 3193.624 us; speedup vs baseline: 7.9575x; 1.4721x over previous
//
#include <hip/hip_runtime.h>

#define TT 512
#define BB 1024
#define FF 32
#define HH 64
#define GG 256   // 4*H gates per direction

// Static device scratch (ws_size-independent). Fully overwritten every call.
__device__ float g_h1[(size_t)TT * BB * 2 * HH];   // [T][B][128] layer-1 input, 256 MB
__device__ float g_pre0[(size_t)2 * TT * BB * GG]; // [dir][T][B][256] layer-0 pre-gates, 1.07 GB
__device__ float g_pre1[(size_t)TT * BB * GG];     // [T][B][256] layer-1 fwd pre-gates, 537 MB
__device__ float g_hf[(size_t)BB * HH];            // [B][64] final fwd h of layer1

__device__ __forceinline__ float fsigm(float x) {
    float e = __builtin_amdgcn_exp2f(x * -1.44269504088896f);
    return __builtin_amdgcn_rcpf(1.0f + e);
}
__device__ __forceinline__ float ftanh(float x) {
    float e = __builtin_amdgcn_exp2f(x * -2.88539008177793f);
    return 2.0f * __builtin_amdgcn_rcpf(1.0f + e) - 1.0f;
}
// Wave-uniform broadcast via v_readlane (VALU->SGPR, zero LDS-pipe cost).
__device__ __forceinline__ float rlane(float v, int l) {
    return __int_as_float(__builtin_amdgcn_readlane(__float_as_int(v), l));
}

// 2-batch h-matvec quad: h_flat[b*64+j] staged as float4 #(b*16+j4) in lanes
// 0..31 (comp c of hs0..hs3). acc_b += sum_c h[b][4*J4+c]*w[gate][4*J4+c].
#define HM2(J4, WQ) do{                                                       \
    acc0 += rlane(hs0,(J4)   )*(WQ).x + rlane(hs1,(J4)   )*(WQ).y             \
          + rlane(hs2,(J4)   )*(WQ).z + rlane(hs3,(J4)   )*(WQ).w;            \
    acc1 += rlane(hs0,16+(J4))*(WQ).x + rlane(hs1,16+(J4))*(WQ).y             \
          + rlane(hs2,16+(J4))*(WQ).z + rlane(hs3,16+(J4))*(WQ).w;            \
}while(0)
// 1-batch variant: h staged in lanes 0..15.
#define HM1(J4, WQ) do{                                                       \
    acc0 += rlane(hs0,(J4)   )*(WQ).x + rlane(hs1,(J4)   )*(WQ).y             \
          + rlane(hs2,(J4)   )*(WQ).z + rlane(hs3,(J4)   )*(WQ).w;            \
}while(0)

// ---------------------------------------------------------------------------
// Layer-0 input pre-gates (unchanged from r9).
// ---------------------------------------------------------------------------
__global__ __launch_bounds__(256, 4) void pre_gemm0(
    const float* __restrict__ x,      // [B][T][F]
    const float* __restrict__ w_ih,   // [2][G][F]
    const float* __restrict__ b_ih,
    const float* __restrict__ b_hh)
{
    const int tid = threadIdx.x;          // gate
    const int b   = blockIdx.x >> 1;
    const int dir = blockIdx.x & 1;

    __shared__ __align__(16) float4 w4[8 * 256];    // [kq][gate], 32 KB
    __shared__ __align__(16) float xbuf[2][256];    // 8 t-rows x 32 f, dbuf

    const float4* wsrc = (const float4*)(w_ih + ((size_t)dir * GG + tid) * FF);
#pragma unroll
    for (int kq = 0; kq < 8; ++kq) w4[kq * 256 + tid] = wsrc[kq];
    const float bias = b_ih[dir * GG + tid] + b_hh[dir * GG + tid];

    const float* xbase = x + (size_t)b * TT * FF;
    xbuf[0][tid] = xbase[tid];            // tile 0 (rows 0..7), coalesced
    const size_t OS = (size_t)BB * GG;

    for (int tc = 0; tc < 64; ++tc) {
        const int cur = tc & 1;
        __syncthreads();   // xbuf[cur] ready; prev reads of xbuf[1-cur] done

        float vnext = 0.f;
        if (tc + 1 < 64) vnext = xbase[(tc + 1) * 256 + tid];   // coalesced

        float a0 = bias, a1 = bias, a2 = bias, a3 = bias,
              a4 = bias, a5 = bias, a6 = bias, a7 = bias;
#pragma unroll
        for (int kq = 0; kq < 8; ++kq) {
            float4 wq = w4[kq * 256 + tid];
            const float4* xr = (const float4*)xbuf[cur];
            float4 q;
            q = xr[0 * 8 + kq]; a0 += q.x*wq.x + q.y*wq.y + q.z*wq.z + q.w*wq.w;
            q = xr[1 * 8 + kq]; a1 += q.x*wq.x + q.y*wq.y + q.z*wq.z + q.w*wq.w;
            q = xr[2 * 8 + kq]; a2 += q.x*wq.x + q.y*wq.y + q.z*wq.z + q.w*wq.w;
            q = xr[3 * 8 + kq]; a3 += q.x*wq.x + q.y*wq.y + q.z*wq.z + q.w*wq.w;
            q = xr[4 * 8 + kq]; a4 += q.x*wq.x + q.y*wq.y + q.z*wq.z + q.w*wq.w;
            q = xr[5 * 8 + kq]; a5 += q.x*wq.x + q.y*wq.y + q.z*wq.z + q.w*wq.w;
            q = xr[6 * 8 + kq]; a6 += q.x*wq.x + q.y*wq.y + q.z*wq.z + q.w*wq.w;
            q = xr[7 * 8 + kq]; a7 += q.x*wq.x + q.y*wq.y + q.z*wq.z + q.w*wq.w;
        }
        float* op = g_pre0 + (((size_t)dir * TT + tc * 8) * BB + b) * GG + tid;
        op[0] = a0; op[1 * OS] = a1; op[2 * OS] = a2; op[3 * OS] = a3;
        op[4 * OS] = a4; op[5 * OS] = a5; op[6 * OS] = a6; op[7 * OS] = a7;

        if (tc + 1 < 64) xbuf[1 - cur][tid] = vnext;
    }
}

// ---------------------------------------------------------------------------
// Layer 0 recurrent-only scan, v2: 1024 blocks (dir = bid&1, 2 batches)
// x 256 thr (thread = gate). Weight quads 0..11 in regs (48 VGPR), 12..15 in
// 16 KB LDS -> 4 blocks/CU = 16 waves/CU (r9 had 8; VALUBusy 72% said stalls,
// so double the waves to soak them).
// ---------------------------------------------------------------------------
__global__ __launch_bounds__(256, 4) void lstm_layer0_scan(
    const float* __restrict__ w_hh)   // [2][G][64]
{
    const int tid  = threadIdx.x;
    const int dir  = blockIdx.x & 1;
    const int b0   = (blockIdx.x >> 1) * 2;
    const int lane = tid & 63;

    __shared__ __align__(16) float4 wlds[4 * 256];   // quads 12..15, 16 KB
    __shared__ float gact[2][GG];
    __shared__ __align__(16) float hbuf[256];        // 128 used (b*64+j), padded

    const float4* wsrc = (const float4*)(w_hh + (size_t)dir * GG * HH) + (size_t)tid * 16;
    float4 w0 = wsrc[0],  w1 = wsrc[1],  w2 = wsrc[2],  w3 = wsrc[3],
           w4 = wsrc[4],  w5 = wsrc[5],  w6 = wsrc[6],  w7 = wsrc[7],
           w8 = wsrc[8],  w9 = wsrc[9],  w10 = wsrc[10], w11 = wsrc[11];
#pragma unroll
    for (int i = 0; i < 4; ++i) wlds[i * 256 + tid] = wsrc[12 + i];
    __syncthreads();

    float c_reg = 0.f;
    float hs0 = 0.f, hs1 = 0.f, hs2 = 0.f, hs3 = 0.f;
    const int cb = (tid >> 6) & 1, cj = tid & 63;    // cell role (tid < 128)
    const bool is_g = ((tid >> 6) == 2);             // gate 128..191 -> tanh

    const size_t DOFF = (size_t)dir * TT;
    const int t0 = dir ? (TT - 1) : 0;
    float p0 = g_pre0[((DOFF + t0) * BB + (b0 + 0)) * GG + tid];
    float p1 = g_pre0[((DOFF + t0) * BB + (b0 + 1)) * GG + tid];

    for (int s = 0; s < TT; ++s) {
        const int t = dir ? (TT - 1 - s) : s;
        float n0 = 0.f, n1 = 0.f;
        if (s + 1 < TT) {
            int tn = dir ? (TT - 2 - s) : (s + 1);
            n0 = g_pre0[((DOFF + tn) * BB + (b0 + 0)) * GG + tid];
            n1 = g_pre0[((DOFF + tn) * BB + (b0 + 1)) * GG + tid];
        }
        float acc0 = p0, acc1 = p1;
        HM2(0, w0);  HM2(1, w1);  HM2(2, w2);   HM2(3, w3);
        HM2(4, w4);  HM2(5, w5);  HM2(6, w6);   HM2(7, w7);
        HM2(8, w8);  HM2(9, w9);  HM2(10, w10); HM2(11, w11);
#pragma unroll
        for (int i = 0; i < 4; ++i) {
            float4 wq = wlds[i * 256 + tid];
            HM2(12 + i, wq);
        }
        gact[0][tid] = is_g ? ftanh(acc0) : fsigm(acc0);
        gact[1][tid] = is_g ? ftanh(acc1) : fsigm(acc1);
        __syncthreads();   // gact ready

        if (tid < 128) {
            float ig = gact[cb][cj];
            float fg = gact[cb][HH + cj];
            float gg = gact[cb][2 * HH + cj];
            float og = gact[cb][3 * HH + cj];
            c_reg = fg * c_reg + ig * gg;
            float h = og * ftanh(c_reg);
            hbuf[tid] = h;   // tid == cb*64+cj
            g_h1[((size_t)t * BB + (b0 + cb)) * (2 * HH) + dir * HH + cj] = h;
        }
        __syncthreads();   // hbuf ready; gact reads done

        float4 hv = ((const float4*)hbuf)[lane & 31];
        hs0 = hv.x; hs1 = hv.y; hs2 = hv.z; hs3 = hv.w;
        p0 = n0; p1 = n1;
    }
}

// ---------------------------------------------------------------------------
// Layer-1 forward input pre-gates (unchanged from r9).
// ---------------------------------------------------------------------------
__global__ __launch_bounds__(256, 2) void pre_gemm1(
    const float* __restrict__ w_ih,   // [2][G][128] (dir 0 used)
    const float* __restrict__ b_ih,
    const float* __restrict__ b_hh)
{
    const int tid  = threadIdx.x;
    const int gl   = tid & 127;
    const int rg   = tid >> 7;
    const int b    = blockIdx.x >> 1;
    const int gate = (blockIdx.x & 1) * 128 + gl;

    __shared__ __align__(16) float4 w4[28 * 128];       // quads 0..27, 56 KB
    __shared__ __align__(16) float4 hstg[2][8 * 32];    // 8 t-rows x 32 q, dbuf 8 KB

    const float4* wsrc = (const float4*)w_ih + (size_t)gate * 32;
#pragma unroll
    for (int i = 0; i < 14; ++i) {
        int kq = rg * 14 + i;
        w4[kq * 128 + gl] = wsrc[kq];
    }
    float4 wr0 = wsrc[28], wr1 = wsrc[29], wr2 = wsrc[30], wr3 = wsrc[31];
    const float bias = b_ih[gate] + b_hh[gate];

    const int srow = tid >> 5, sq = tid & 31;
    hstg[0][srow * 32 + sq] =
        *((const float4*)(g_h1 + ((size_t)srow * BB + b) * 128) + sq);

    const size_t RS = (size_t)BB * GG;    // pre1 t-stride (floats)

    for (int tc = 0; tc < 64; ++tc) {
        const int cur = tc & 1;
        __syncthreads();   // hstg[cur] + w4 ready

        float4 vnext = make_float4(0.f, 0.f, 0.f, 0.f);
        if (tc + 1 < 64)
            vnext = *((const float4*)(g_h1 +
                      ((size_t)((tc + 1) * 8 + srow) * BB + b) * 128) + sq);

        const float4* hr0 = &hstg[cur][(rg * 4 + 0) * 32];
        const float4* hr1 = &hstg[cur][(rg * 4 + 1) * 32];
        const float4* hr2 = &hstg[cur][(rg * 4 + 2) * 32];
        const float4* hr3 = &hstg[cur][(rg * 4 + 3) * 32];

        float a0 = bias, a1 = bias, a2 = bias, a3 = bias;
#pragma unroll
        for (int kq = 0; kq < 28; ++kq) {
            float4 wq = w4[kq * 128 + gl];
            float4 q;
            q = hr0[kq]; a0 += q.x*wq.x + q.y*wq.y + q.z*wq.z + q.w*wq.w;
            q = hr1[kq]; a1 += q.x*wq.x + q.y*wq.y + q.z*wq.z + q.w*wq.w;
            q = hr2[kq]; a2 += q.x*wq.x + q.y*wq.y + q.z*wq.z + q.w*wq.w;
            q = hr3[kq]; a3 += q.x*wq.x + q.y*wq.y + q.z*wq.z + q.w*wq.w;
        }
        {
            float4 q;
            q = hr0[28]; a0 += q.x*wr0.x + q.y*wr0.y + q.z*wr0.z + q.w*wr0.w;
            q = hr1[28]; a1 += q.x*wr0.x + q.y*wr0.y + q.z*wr0.z + q.w*wr0.w;
            q = hr2[28]; a2 += q.x*wr0.x + q.y*wr0.y + q.z*wr0.z + q.w*wr0.w;
            q = hr3[28]; a3 += q.x*wr0.x + q.y*wr0.y + q.z*wr0.z + q.w*wr0.w;
            q = hr0[29]; a0 += q.x*wr1.x + q.y*wr1.y + q.z*wr1.z + q.w*wr1.w;
            q = hr1[29]; a1 += q.x*wr1.x + q.y*wr1.y + q.z*wr1.z + q.w*wr1.w;
            q = hr2[29]; a2 += q.x*wr1.x + q.y*wr1.y + q.z*wr1.z + q.w*wr1.w;
            q = hr3[29]; a3 += q.x*wr1.x + q.y*wr1.y + q.z*wr1.z + q.w*wr1.w;
            q = hr0[30]; a0 += q.x*wr2.x + q.y*wr2.y + q.z*wr2.z + q.w*wr2.w;
            q = hr1[30]; a1 += q.x*wr2.x + q.y*wr2.y + q.z*wr2.z + q.w*wr2.w;
            q = hr2[30]; a2 += q.x*wr2.x + q.y*wr2.y + q.z*wr2.z + q.w*wr2.w;
            q = hr3[30]; a3 += q.x*wr2.x + q.y*wr2.y + q.z*wr2.z + q.w*wr2.w;
            q = hr0[31]; a0 += q.x*wr3.x + q.y*wr3.y + q.z*wr3.z + q.w*wr3.w;
            q = hr1[31]; a1 += q.x*wr3.x + q.y*wr3.y + q.z*wr3.z + q.w*wr3.w;
            q = hr2[31]; a2 += q.x*wr3.x + q.y*wr3.y + q.z*wr3.z + q.w*wr3.w;
            q = hr3[31]; a3 += q.x*wr3.x + q.y*wr3.y + q.z*wr3.z + q.w*wr3.w;
        }
        {
            const int tb = tc * 8 + rg * 4;
            float* op = g_pre1 + ((size_t)tb * BB + b) * GG + gate;
            op[0 * RS] = a0; op[1 * RS] = a1; op[2 * RS] = a2; op[3 * RS] = a3;
        }
        if (tc + 1 < 64) hstg[1 - cur][srow * 32 + sq] = vnext;
    }
}

// ---------------------------------------------------------------------------
// Layer 1 forward scan, v2: 1024 blocks x 256 thr, ONE batch per block.
// Same reg/LDS weight split as layer0_scan v2 -> 4 blocks/CU = 16 waves/CU.
// ---------------------------------------------------------------------------
__global__ __launch_bounds__(256, 4) void lstm_layer1_fwd(
    const float* __restrict__ w_hh)   // [2][G][64] (dir 0 used)
{
    const int tid  = threadIdx.x;
    const int b    = blockIdx.x;
    const int lane = tid & 63;

    __shared__ __align__(16) float4 wlds[4 * 256];   // quads 12..15, 16 KB
    __shared__ float gact[GG];
    __shared__ __align__(16) float hbuf[256];        // 64 used, padded

    const float4* wsrc = (const float4*)w_hh + (size_t)tid * 16;
    float4 w0 = wsrc[0],  w1 = wsrc[1],  w2 = wsrc[2],  w3 = wsrc[3],
           w4 = wsrc[4],  w5 = wsrc[5],  w6 = wsrc[6],  w7 = wsrc[7],
           w8 = wsrc[8],  w9 = wsrc[9],  w10 = wsrc[10], w11 = wsrc[11];
#pragma unroll
    for (int i = 0; i < 4; ++i) wlds[i * 256 + tid] = wsrc[12 + i];
    __syncthreads();

    float c_reg = 0.f;
    float hs0 = 0.f, hs1 = 0.f, hs2 = 0.f, hs3 = 0.f;
    const int cj = tid & 63;
    const bool is_g = ((tid >> 6) == 2);

    float p0 = g_pre1[((size_t)0 * BB + b) * GG + tid];

    for (int t = 0; t < TT; ++t) {
        float n0 = 0.f;
        if (t + 1 < TT)
            n0 = g_pre1[((size_t)(t + 1) * BB + b) * GG + tid];

        float acc0 = p0;
        HM1(0, w0);  HM1(1, w1);  HM1(2, w2);   HM1(3, w3);
        HM1(4, w4);  HM1(5, w5);  HM1(6, w6);   HM1(7, w7);
        HM1(8, w8);  HM1(9, w9);  HM1(10, w10); HM1(11, w11);
#pragma unroll
        for (int i = 0; i < 4; ++i) {
            float4 wq = wlds[i * 256 + tid];
            HM1(12 + i, wq);
        }
        gact[tid] = is_g ? ftanh(acc0) : fsigm(acc0);
        __syncthreads();   // gact ready

        if (tid < 64) {
            float ig = gact[cj];
            float fg = gact[HH + cj];
            float gg = gact[2 * HH + cj];
            float og = gact[3 * HH + cj];
            c_reg = fg * c_reg + ig * gg;
            float h = og * ftanh(c_reg);
            hbuf[tid] = h;
            if (t == TT - 1) g_hf[(size_t)b * HH + cj] = h;
        }
        __syncthreads();   // hbuf ready

        float4 hv = ((const float4*)hbuf)[lane & 15];
        hs0 = hv.x; hs1 = hv.y; hs2 = hv.z; hs3 = hv.w;
        p0 = n0;
    }
}

// ---------------------------------------------------------------------------
// Layer 1 backward single step (zero state on h1[T-1]) + FC head.
// Unchanged from r9 (runs once; cost negligible).
// ---------------------------------------------------------------------------
#define FMAC4(W, P0, P1, P2, P3, K) do{                                   \
    float4 v_;                                                           \
    v_ = (P0)[K]; acc0 += W.x*v_.x; acc0 += W.y*v_.y; acc0 += W.z*v_.z; acc0 += W.w*v_.w; \
    v_ = (P1)[K]; acc1 += W.x*v_.x; acc1 += W.y*v_.y; acc1 += W.z*v_.z; acc1 += W.w*v_.w; \
    v_ = (P2)[K]; acc2 += W.x*v_.x; acc2 += W.y*v_.y; acc2 += W.z*v_.z; acc2 += W.w*v_.w; \
    v_ = (P3)[K]; acc3 += W.x*v_.x; acc3 += W.y*v_.y; acc3 += W.z*v_.z; acc3 += W.w*v_.w; \
}while(0)

__global__ __launch_bounds__(256, 2) void lstm_final(
    const float* __restrict__ w_ih,   // [2][G][128] (dir 1)
    const float* __restrict__ b_ih,
    const float* __restrict__ b_hh,
    const float* __restrict__ fc_w,   // [2][128]
    const float* __restrict__ fc_b,   // [2]
    float* __restrict__ out)          // [B][2]
{
    const int tid = threadIdx.x;
    const int b0  = blockIdx.x * 4;

    __shared__ __align__(16) float x_lds[4][128];
    __shared__ __align__(16) float gact[4][GG];
    __shared__ __align__(16) float last[4][128];

#pragma unroll
    for (int r = 0; r < 2; ++r) {
        int idx = tid + r * 256;
        int b = idx >> 7, col = idx & 127;
        x_lds[b][col] = g_h1[((size_t)(TT - 1) * BB + (b0 + b)) * 128 + col];
    }

    const float4* p = (const float4*)(w_ih + ((size_t)GG + tid) * 128);
    float4 w0 = p[0],  w1 = p[1],  w2 = p[2],  w3 = p[3],  w4 = p[4],  w5 = p[5],
           w6 = p[6],  w7 = p[7],  w8 = p[8],  w9 = p[9],  w10 = p[10], w11 = p[11],
           w12 = p[12], w13 = p[13], w14 = p[14], w15 = p[15], w16 = p[16], w17 = p[17],
           w18 = p[18], w19 = p[19], w20 = p[20], w21 = p[21], w22 = p[22], w23 = p[23],
           w24 = p[24], w25 = p[25], w26 = p[26], w27 = p[27], w28 = p[28], w29 = p[29],
           w30 = p[30], w31 = p[31];
    const float bias = b_ih[GG + tid] + b_hh[GG + tid];
    __syncthreads();

    const float4* xb0 = (const float4*)x_lds[0];
    const float4* xb1 = (const float4*)x_lds[1];
    const float4* xb2 = (const float4*)x_lds[2];
    const float4* xb3 = (const float4*)x_lds[3];

    float acc0 = bias, acc1 = bias, acc2 = bias, acc3 = bias;
    FMAC4(w0, xb0, xb1, xb2, xb3, 0);   FMAC4(w1, xb0, xb1, xb2, xb3, 1);
    FMAC4(w2, xb0, xb1, xb2, xb3, 2);   FMAC4(w3, xb0, xb1, xb2, xb3, 3);
    FMAC4(w4, xb0, xb1, xb2, xb3, 4);   FMAC4(w5, xb0, xb1, xb2, xb3, 5);
    FMAC4(w6, xb0, xb1, xb2, xb3, 6);   FMAC4(w7, xb0, xb1, xb2, xb3, 7);
    FMAC4(w8, xb0, xb1, xb2, xb3, 8);   FMAC4(w9, xb0, xb1, xb2, xb3, 9);
    FMAC4(w10, xb0, xb1, xb2, xb3, 10); FMAC4(w11, xb0, xb1, xb2, xb3, 11);
    FMAC4(w12, xb0, xb1, xb2, xb3, 12); FMAC4(w13, xb0, xb1, xb2, xb3, 13);
    FMAC4(w14, xb0, xb1, xb2, xb3, 14); FMAC4(w15, xb0, xb1, xb2, xb3, 15);
    FMAC4(w16, xb0, xb1, xb2, xb3, 16); FMAC4(w17, xb0, xb1, xb2, xb3, 17);
    FMAC4(w18, xb0, xb1, xb2, xb3, 18); FMAC4(w19, xb0, xb1, xb2, xb3, 19);
    FMAC4(w20, xb0, xb1, xb2, xb3, 20); FMAC4(w21, xb0, xb1, xb2, xb3, 21);
    FMAC4(w22, xb0, xb1, xb2, xb3, 22); FMAC4(w23, xb0, xb1, xb2, xb3, 23);
    FMAC4(w24, xb0, xb1, xb2, xb3, 24); FMAC4(w25, xb0, xb1, xb2, xb3, 25);
    FMAC4(w26, xb0, xb1, xb2, xb3, 26); FMAC4(w27, xb0, xb1, xb2, xb3, 27);
    FMAC4(w28, xb0, xb1, xb2, xb3, 28); FMAC4(w29, xb0, xb1, xb2, xb3, 29);
    FMAC4(w30, xb0, xb1, xb2, xb3, 30); FMAC4(w31, xb0, xb1, xb2, xb3, 31);

    const bool is_g = ((tid >> 6) == 2);
    gact[0][tid] = is_g ? ftanh(acc0) : fsigm(acc0);
    gact[1][tid] = is_g ? ftanh(acc1) : fsigm(acc1);
    gact[2][tid] = is_g ? ftanh(acc2) : fsigm(acc2);
    gact[3][tid] = is_g ? ftanh(acc3) : fsigm(acc3);
    __syncthreads();

    {
        const int cb = tid >> 6, cj = tid & 63;
        float ig = gact[cb][cj];
        float gg = gact[cb][2 * HH + cj];
        float og = gact[cb][3 * HH + cj];
        float c = ig * gg;
        float h = og * ftanh(c);
        last[cb][HH + cj] = h;
        last[cb][cj] = g_hf[(size_t)(b0 + cb) * HH + cj];
    }
    __syncthreads();

    if (tid < 8) {
        int b = tid >> 1, o = tid & 1;
        float a = fc_b[o];
#pragma unroll
        for (int j = 0; j < 128; ++j) a += fc_w[o * 128 + j] * last[b][j];
        out[(size_t)(b0 + b) * 2 + o] = a;
    }
}

extern "C" void kernel_launch(void* const* d_in, const int* in_sizes, int n_in,
                              void* d_out, int out_size, void* d_ws, size_t ws_size,
                              hipStream_t stream) {
    const float* x     = (const float*)d_in[0];
    const float* w_ih0 = (const float*)d_in[1];
    const float* w_hh0 = (const float*)d_in[2];
    const float* b_ih0 = (const float*)d_in[3];
    const float* b_hh0 = (const float*)d_in[4];
    const float* w_ih1 = (const float*)d_in[5];
    const float* w_hh1 = (const float*)d_in[6];
    const float* b_ih1 = (const float*)d_in[7];
    const float* b_hh1 = (const float*)d_in[8];
    const float* fc_w  = (const float*)d_in[9];
    const float* fc_b  = (const float*)d_in[10];
    float* out = (float*)d_out;

    pre_gemm0<<<2048, 256, 0, stream>>>(x, w_ih0, b_ih0, b_hh0);
    lstm_layer0_scan<<<1024, 256, 0, stream>>>(w_hh0);
    pre_gemm1<<<2048, 256, 0, stream>>>(w_ih1, b_ih1, b_hh1);
    lstm_layer1_fwd<<<1024, 256, 0, stream>>>(w_hh1);
    lstm_final<<<256, 256, 0, stream>>>(w_ih1, b_ih1, b_hh1, fc_w, fc_b, out);
}